// Round 1
// baseline (2262.692 us; speedup 1.0000x reference)
//
#include <hip/hip_runtime.h>
#include <hip/hip_bf16.h>
#include <math.h>

// Problem constants
#define B_   16
#define L_   196
#define FD_  2048
#define N_   1000
#define WD_  300
#define HD_  512
#define DD_  5
#define E_   50000
#define TMAX_ 5
#define NIMG_ 1000

// ---------------------------------------------------------------------------
// Generic tiled fp32 GEMM: C[b] = act(A[b] @ B[b] (+bias))
// A: [M,K] row-major. B: [K,N] row-major, or [N,K] row-major if TB.
// 64x64 tile, 256 threads, 4x4 micro-tile, K-tile 16.
// ---------------------------------------------------------------------------
template<bool TB, bool RELU>
__global__ __launch_bounds__(256) void gemm_k(
    const float* __restrict__ A, const float* __restrict__ Bm,
    const float* __restrict__ bias, float* __restrict__ C,
    int M, int N, int K, long sA, long sB, long sC)
{
    __shared__ float As[16][65];
    __shared__ float Bs[16][65];
    long zb = blockIdx.z;
    A += zb * sA; Bm += zb * sB; C += zb * sC;
    int t  = threadIdx.x;
    int tx = t & 15, ty = t >> 4;
    int row0 = blockIdx.y * 64, col0 = blockIdx.x * 64;
    float acc[4][4] = {};
    for (int k0 = 0; k0 < K; k0 += 16) {
        #pragma unroll
        for (int i = 0; i < 4; i++) {
            int idx = t + i * 256;
            int m = idx >> 4, kk = idx & 15;
            int gm = row0 + m, gk = k0 + kk;
            As[kk][m] = (gm < M && gk < K) ? A[(long)gm * K + gk] : 0.f;
        }
        #pragma unroll
        for (int i = 0; i < 4; i++) {
            int idx = t + i * 256;
            int nn, kk;
            if (TB) { nn = idx >> 4; kk = idx & 15; }
            else    { kk = idx >> 6; nn = idx & 63; }
            int gn = col0 + nn, gk = k0 + kk;
            float v = 0.f;
            if (gn < N && gk < K) v = TB ? Bm[(long)gn * K + gk] : Bm[(long)gk * N + gn];
            Bs[kk][nn] = v;
        }
        __syncthreads();
        #pragma unroll
        for (int kk = 0; kk < 16; kk++) {
            float a[4], b[4];
            #pragma unroll
            for (int i = 0; i < 4; i++) a[i] = As[kk][ty * 4 + i];
            #pragma unroll
            for (int j = 0; j < 4; j++) b[j] = Bs[kk][tx * 4 + j];
            #pragma unroll
            for (int i = 0; i < 4; i++)
                #pragma unroll
                for (int j = 0; j < 4; j++) acc[i][j] = fmaf(a[i], b[j], acc[i][j]);
        }
        __syncthreads();
    }
    #pragma unroll
    for (int i = 0; i < 4; i++) {
        int gm = row0 + ty * 4 + i;
        if (gm >= M) continue;
        #pragma unroll
        for (int j = 0; j < 4; j++) {
            int gn = col0 + tx * 4 + j;
            if (gn >= N) continue;
            float v = acc[i][j];
            if (bias) v += bias[gn];
            if (RELU) v = fmaxf(v, 0.f);
            C[(long)gm * N + gn] = v;
        }
    }
}

// ---------------------------------------------------------------------------
// pooled[b,f] = mean_l feats[b,l,f]
// ---------------------------------------------------------------------------
__global__ void pooled_kernel(const float* __restrict__ feats, float* __restrict__ pooled)
{
    int idx = blockIdx.x * blockDim.x + threadIdx.x;  // B_*FD_
    if (idx >= B_ * FD_) return;
    int b = idx / FD_, f = idx % FD_;
    const float* p = feats + (long)b * L_ * FD_ + f;
    float acc = 0.f;
    for (int l = 0; l < L_; l++) acc += p[(long)l * FD_];
    pooled[idx] = acc * (1.0f / L_);
}

// ---------------------------------------------------------------------------
// clf logits: out[b,n] = pooled[b,:] . W_clf[:,n] + b_clf[n]
// ---------------------------------------------------------------------------
__global__ void clf_kernel(const float* __restrict__ pooled, const float* __restrict__ W,
                           const float* __restrict__ bias, float* __restrict__ out)
{
    int idx = blockIdx.x * blockDim.x + threadIdx.x;  // 16*1000
    if (idx >= B_ * NIMG_) return;
    int b = idx / NIMG_, n = idx % NIMG_;
    const float* p = pooled + b * FD_;
    float acc = bias[n];
    for (int k = 0; k < FD_; k++) acc = fmaf(p[k], W[(long)k * NIMG_ + n], acc);
    out[idx] = acc;
}

// ---------------------------------------------------------------------------
// in-place row softmax, one wave per row
// ---------------------------------------------------------------------------
template<int NCOLS>
__global__ void softmax_rows(float* __restrict__ X, int rows)
{
    int gid = blockIdx.x * blockDim.x + threadIdx.x;
    int wave = gid >> 6, lane = gid & 63;
    if (wave >= rows) return;
    float* row = X + (long)wave * NCOLS;
    const int PER = (NCOLS + 63) / 64;
    float v[PER];
    float m = -1e30f;
    int cnt = 0;
    for (int k = lane; k < NCOLS; k += 64) { v[cnt] = row[k]; m = fmaxf(m, v[cnt]); cnt++; }
    #pragma unroll
    for (int off = 32; off; off >>= 1) m = fmaxf(m, __shfl_xor(m, off));
    float s = 0.f;
    for (int i = 0; i < cnt; i++) { v[i] = expf(v[i] - m); s += v[i]; }
    #pragma unroll
    for (int off = 32; off; off >>= 1) s += __shfl_xor(s, off);
    float inv = 1.f / s;
    cnt = 0;
    for (int k = lane; k < NCOLS; k += 64) row[k] = v[cnt++] * inv;
}

// ---------------------------------------------------------------------------
// h0[r,d] = h1[r,:] @ Wf2[:,d] + bf2[d]   (one wave per row, K=512)
// ---------------------------------------------------------------------------
__global__ void h0_kernel(const float* __restrict__ h1, const float* __restrict__ Wf2,
                          const float* __restrict__ bf2, float* __restrict__ h0, int rows)
{
    int gid = blockIdx.x * blockDim.x + threadIdx.x;
    int wave = gid >> 6, lane = gid & 63;
    if (wave >= rows) return;
    const float* row = h1 + (long)wave * HD_;
    float acc[DD_] = {};
    for (int k = lane; k < HD_; k += 64) {
        float v = row[k];
        #pragma unroll
        for (int d = 0; d < DD_; d++) acc[d] = fmaf(v, Wf2[k * DD_ + d], acc[d]);
    }
    #pragma unroll
    for (int d = 0; d < DD_; d++)
        #pragma unroll
        for (int off = 32; off; off >>= 1) acc[d] += __shfl_down(acc[d], off);
    if (lane == 0) {
        #pragma unroll
        for (int d = 0; d < DD_; d++) h0[(long)wave * DD_ + d] = acc[d] + bf2[d];
    }
}

// ---------------------------------------------------------------------------
// zero-fill
// ---------------------------------------------------------------------------
__global__ void zero_kernel(float* __restrict__ p, int n)
{
    int i = blockIdx.x * blockDim.x + threadIdx.x;
    if (i < n) p[i] = 0.f;
}

// ---------------------------------------------------------------------------
// Edge MLP: val[e] = tanh(relu(cat(emb[s],emb[d]) @ Wr1 + br1) @ Wr2 + br2)
// scattered with atomicAdd into prop[s,d]. 8 edges per block, 256 units.
// ---------------------------------------------------------------------------
#define EPB 8
__global__ __launch_bounds__(256) void edge_mlp(
    const float* __restrict__ embed, const int* __restrict__ edges,
    const float* __restrict__ Wr1, const float* __restrict__ br1,
    const float* __restrict__ Wr2, const float* __restrict__ br2,
    float* __restrict__ prop)
{
    __shared__ float et[EPB][2 * WD_];
    __shared__ float partial[4][EPB];
    __shared__ int src[EPB], dst[EPB];
    int e0 = blockIdx.x * EPB;
    int t = threadIdx.x;
    if (t < EPB) { src[t] = edges[e0 + t]; dst[t] = edges[E_ + e0 + t]; }
    __syncthreads();
    for (int i = t; i < EPB * 2 * WD_; i += 256) {
        int ei = i / (2 * WD_), k = i % (2 * WD_);
        int node = (k < WD_) ? src[ei] : dst[ei];
        int kk = (k < WD_) ? k : k - WD_;
        et[ei][k] = embed[node * WD_ + kk];
    }
    __syncthreads();
    float acc[EPB];
    float bb = br1[t];
    #pragma unroll
    for (int ei = 0; ei < EPB; ei++) acc[ei] = bb;
    for (int k = 0; k < 2 * WD_; k++) {
        float w = Wr1[k * 256 + t];
        #pragma unroll
        for (int ei = 0; ei < EPB; ei++) acc[ei] = fmaf(et[ei][k], w, acc[ei]);
    }
    float w2 = Wr2[t];
    int lane = t & 63, wv = t >> 6;
    #pragma unroll
    for (int ei = 0; ei < EPB; ei++) {
        float h = fmaxf(acc[ei], 0.f) * w2;
        #pragma unroll
        for (int off = 32; off; off >>= 1) h += __shfl_down(h, off);
        if (lane == 0) partial[wv][ei] = h;
    }
    __syncthreads();
    if (t < EPB) {
        float s = partial[0][t] + partial[1][t] + partial[2][t] + partial[3][t];
        atomicAdd(&prop[src[t] * N_ + dst[t]], tanhf(s + br2[0]));
    }
}

// ---------------------------------------------------------------------------
// msg[b,n,d] = tanh(sum_m prop[n,m] * hidden[b,m,d]); block per n.
// ---------------------------------------------------------------------------
__global__ __launch_bounds__(128) void msg_kernel(
    const float* __restrict__ prop, const float* __restrict__ hidden,
    float* __restrict__ msg)
{
    int n = blockIdx.x;
    __shared__ float pr[N_];
    int t = threadIdx.x;
    for (int k = t; k < N_; k += 128) pr[k] = prop[(long)n * N_ + k];
    __syncthreads();
    if (t < B_ * DD_) {
        int b = t / DD_, d = t % DD_;
        const float* hb = hidden + (long)b * N_ * DD_ + d;
        float acc = 0.f;
        for (int m = 0; m < N_; m++) acc = fmaf(pr[m], hb[m * DD_], acc);
        msg[((long)b * N_ + n) * DD_ + d] = tanhf(acc);
    }
}

// ---------------------------------------------------------------------------
// GRU cell, thread per row. W_ih/W_hh are [15,5] (torch layout).
// ---------------------------------------------------------------------------
__global__ void gru_kernel(const float* __restrict__ msg, float* __restrict__ hidden,
                           const float* __restrict__ W_ih, const float* __restrict__ b_ih,
                           const float* __restrict__ W_hh, const float* __restrict__ b_hh)
{
    int r = blockIdx.x * blockDim.x + threadIdx.x;
    if (r >= B_ * N_) return;
    float x[DD_], h[DD_];
    #pragma unroll
    for (int i = 0; i < DD_; i++) { x[i] = msg[r * DD_ + i]; h[i] = hidden[r * DD_ + i]; }
    float gi[3 * DD_], gh[3 * DD_];
    #pragma unroll
    for (int g = 0; g < 3 * DD_; g++) {
        float a = b_ih[g], c = b_hh[g];
        #pragma unroll
        for (int k = 0; k < DD_; k++) {
            a = fmaf(x[k], W_ih[g * DD_ + k], a);
            c = fmaf(h[k], W_hh[g * DD_ + k], c);
        }
        gi[g] = a; gh[g] = c;
    }
    #pragma unroll
    for (int i = 0; i < DD_; i++) {
        float rr = 1.f / (1.f + expf(-(gi[i] + gh[i])));
        float zz = 1.f / (1.f + expf(-(gi[DD_ + i] + gh[DD_ + i])));
        float nn = tanhf(gi[2 * DD_ + i] + rr * gh[2 * DD_ + i]);
        hidden[r * DD_ + i] = (1.f - zz) * nn + zz * h[i];
    }
}

// ---------------------------------------------------------------------------
// logits[r] = relu(hidden[r,:] @ Wo1 + bo1) @ Wo2 + bo2  (one wave per row)
// ---------------------------------------------------------------------------
__global__ void out_kernel(const float* __restrict__ hidden, const float* __restrict__ Wo1,
                           const float* __restrict__ bo1, const float* __restrict__ Wo2,
                           const float* __restrict__ bo2, float* __restrict__ logits, int rows)
{
    int gid = blockIdx.x * blockDim.x + threadIdx.x;
    int wave = gid >> 6, lane = gid & 63;
    if (wave >= rows) return;
    float x[DD_];
    #pragma unroll
    for (int i = 0; i < DD_; i++) x[i] = hidden[(long)wave * DD_ + i];
    float acc = 0.f;
    for (int j = lane; j < HD_; j += 64) {
        float h = bo1[j];
        #pragma unroll
        for (int d = 0; d < DD_; d++) h = fmaf(x[d], Wo1[d * HD_ + j], h);
        h = fmaxf(h, 0.f);
        acc = fmaf(h, Wo2[j], acc);
    }
    #pragma unroll
    for (int off = 32; off; off >>= 1) acc += __shfl_down(acc, off);
    if (lane == 0) logits[wave] = acc + bo2[0];
}

// ---------------------------------------------------------------------------
extern "C" void kernel_launch(void* const* d_in, const int* in_sizes, int n_in,
                              void* d_out, int out_size, void* d_ws, size_t ws_size,
                              hipStream_t stream)
{
    const float* feats   = (const float*)d_in[0];
    const float* embed   = (const float*)d_in[1];
    const int*   edges   = (const int*)  d_in[2];
    const float* W_key   = (const float*)d_in[3];
    const float* b_key   = (const float*)d_in[4];
    const float* W_query = (const float*)d_in[5];
    const float* b_query = (const float*)d_in[6];
    const float* Wf1     = (const float*)d_in[7];
    const float* bf1     = (const float*)d_in[8];
    const float* Wf2     = (const float*)d_in[9];
    const float* bf2     = (const float*)d_in[10];
    const float* Wr1     = (const float*)d_in[11];
    const float* br1     = (const float*)d_in[12];
    const float* Wr2     = (const float*)d_in[13];
    const float* br2     = (const float*)d_in[14];
    const float* Wo1     = (const float*)d_in[15];
    const float* bo1     = (const float*)d_in[16];
    const float* Wo2     = (const float*)d_in[17];
    const float* bo2     = (const float*)d_in[18];
    const float* W_ih    = (const float*)d_in[19];
    const float* b_ih    = (const float*)d_in[20];
    const float* W_hh    = (const float*)d_in[21];
    const float* b_hh    = (const float*)d_in[22];
    const float* W_clf   = (const float*)d_in[23];
    const float* b_clf   = (const float*)d_in[24];

    float* out_logits = (float*)d_out;          // [16,1000]
    float* out_attn   = out_logits + B_ * N_;   // [16,1000,196]
    float* out_img    = out_attn + (long)B_ * N_ * L_;  // [16,1000]

    float* ws = (float*)d_ws;
    float* pooled  = ws;  ws += B_ * FD_;          // 32768
    float* keys    = ws;  ws += B_ * L_ * HD_;     // 1605632
    float* F1      = ws;  ws += B_ * L_ * HD_;     // 1605632
    float* queries = ws;  ws += N_ * HD_;          // 512000
    float* h1      = ws;  ws += (long)B_ * N_ * HD_; // 8192000
    float* prop    = ws;  ws += N_ * N_;           // 1000000
    float* hidden  = ws;  ws += B_ * N_ * DD_;     // 80000
    float* msg     = ws;  ws += B_ * N_ * DD_;     // 80000

    // --- imagenet classifier path ---
    pooled_kernel<<<(B_ * FD_ + 255) / 256, 256, 0, stream>>>(feats, pooled);
    clf_kernel<<<(B_ * NIMG_ + 255) / 256, 256, 0, stream>>>(pooled, W_clf, b_clf, out_img);
    softmax_rows<NIMG_><<<(B_ * 64 + 255) / 256, 256, 0, stream>>>(out_img, B_);

    // --- prop matrix (independent, start early) ---
    zero_kernel<<<(N_ * N_ + 255) / 256, 256, 0, stream>>>(prop, N_ * N_);
    edge_mlp<<<E_ / EPB, 256, 0, stream>>>(embed, edges, Wr1, br1, Wr2, br2, prop);

    // --- attention path ---
    // keys = feats @ W_key + b_key   [3136, 512]
    {
        dim3 g(HD_ / 64, (B_ * L_ + 63) / 64, 1);
        gemm_k<false, false><<<g, 256, 0, stream>>>(feats, W_key, b_key, keys,
                                                    B_ * L_, HD_, FD_, 0, 0, 0);
    }
    // F1 = feats @ Wf1 (no bias)    [3136, 512]
    {
        dim3 g(HD_ / 64, (B_ * L_ + 63) / 64, 1);
        gemm_k<false, false><<<g, 256, 0, stream>>>(feats, Wf1, nullptr, F1,
                                                    B_ * L_, HD_, FD_, 0, 0, 0);
    }
    // queries = embed @ W_query + b_query  [1000, 512]
    {
        dim3 g(HD_ / 64, (N_ + 63) / 64, 1);
        gemm_k<false, false><<<g, 256, 0, stream>>>(embed, W_query, b_query, queries,
                                                    N_, HD_, WD_, 0, 0, 0);
    }
    // scores[b] = queries @ keys[b]^T -> out_attn   [16][1000,196]
    {
        dim3 g((L_ + 63) / 64, (N_ + 63) / 64, B_);
        gemm_k<true, false><<<g, 256, 0, stream>>>(queries, keys, nullptr, out_attn,
                                                   N_, L_, HD_,
                                                   0, (long)L_ * HD_, (long)N_ * L_);
    }
    // softmax over 196, in place in out_attn
    softmax_rows<L_><<<(B_ * N_ * 64 + 255) / 256, 256, 0, stream>>>(out_attn, B_ * N_);

    // h1 = relu(attn @ F1 + bf1)   [16][1000,512]
    {
        dim3 g(HD_ / 64, (N_ + 63) / 64, B_);
        gemm_k<false, true><<<g, 256, 0, stream>>>(out_attn, F1, bf1, h1,
                                                   N_, HD_, L_,
                                                   (long)N_ * L_, (long)L_ * HD_, (long)N_ * HD_);
    }
    // hidden = h1 @ Wf2 + bf2   [16000, 5]
    h0_kernel<<<(B_ * N_ * 64 + 255) / 256, 256, 0, stream>>>(h1, Wf2, bf2, hidden, B_ * N_);

    // --- recurrence ---
    for (int step = 0; step < TMAX_; step++) {
        msg_kernel<<<N_, 128, 0, stream>>>(prop, hidden, msg);
        gru_kernel<<<(B_ * N_ + 255) / 256, 256, 0, stream>>>(msg, hidden, W_ih, b_ih, W_hh, b_hh);
    }

    // --- output head ---
    out_kernel<<<(B_ * N_ * 64 + 255) / 256, 256, 0, stream>>>(hidden, Wo1, bo1, Wo2, bo2,
                                                               out_logits, B_ * N_);
}

// Round 2
// 2162.988 us; speedup vs baseline: 1.0461x; 1.0461x over previous
//
#include <hip/hip_runtime.h>
#include <hip/hip_bf16.h>
#include <math.h>

// Problem constants
#define B_   16
#define L_   196
#define FD_  2048
#define N_   1000
#define WD_  300
#define HD_  512
#define DD_  5
#define E_   50000
#define TMAX_ 5
#define NIMG_ 1000

// ---------------------------------------------------------------------------
// Generic tiled fp32 GEMM: C[b] = act(A[b] @ B[b] (+bias))
// A: [M,K] row-major. B: [K,N] row-major, or [N,K] row-major if TB.
// 64x64 tile, 256 threads, 4x4 micro-tile, K-tile 16.
// ---------------------------------------------------------------------------
template<bool TB, bool RELU>
__global__ __launch_bounds__(256) void gemm_k(
    const float* __restrict__ A, const float* __restrict__ Bm,
    const float* __restrict__ bias, float* __restrict__ C,
    int M, int N, int K, long sA, long sB, long sC)
{
    __shared__ float As[16][65];
    __shared__ float Bs[16][65];
    long zb = blockIdx.z;
    A += zb * sA; Bm += zb * sB; C += zb * sC;
    int t  = threadIdx.x;
    int tx = t & 15, ty = t >> 4;
    int row0 = blockIdx.y * 64, col0 = blockIdx.x * 64;
    float acc[4][4] = {};
    for (int k0 = 0; k0 < K; k0 += 16) {
        #pragma unroll
        for (int i = 0; i < 4; i++) {
            int idx = t + i * 256;
            int m = idx >> 4, kk = idx & 15;
            int gm = row0 + m, gk = k0 + kk;
            As[kk][m] = (gm < M && gk < K) ? A[(long)gm * K + gk] : 0.f;
        }
        #pragma unroll
        for (int i = 0; i < 4; i++) {
            int idx = t + i * 256;
            int nn, kk;
            if (TB) { nn = idx >> 4; kk = idx & 15; }
            else    { kk = idx >> 6; nn = idx & 63; }
            int gn = col0 + nn, gk = k0 + kk;
            float v = 0.f;
            if (gn < N && gk < K) v = TB ? Bm[(long)gn * K + gk] : Bm[(long)gk * N + gn];
            Bs[kk][nn] = v;
        }
        __syncthreads();
        #pragma unroll
        for (int kk = 0; kk < 16; kk++) {
            float a[4], b[4];
            #pragma unroll
            for (int i = 0; i < 4; i++) a[i] = As[kk][ty * 4 + i];
            #pragma unroll
            for (int j = 0; j < 4; j++) b[j] = Bs[kk][tx * 4 + j];
            #pragma unroll
            for (int i = 0; i < 4; i++)
                #pragma unroll
                for (int j = 0; j < 4; j++) acc[i][j] = fmaf(a[i], b[j], acc[i][j]);
        }
        __syncthreads();
    }
    #pragma unroll
    for (int i = 0; i < 4; i++) {
        int gm = row0 + ty * 4 + i;
        if (gm >= M) continue;
        #pragma unroll
        for (int j = 0; j < 4; j++) {
            int gn = col0 + tx * 4 + j;
            if (gn >= N) continue;
            float v = acc[i][j];
            if (bias) v += bias[gn];
            if (RELU) v = fmaxf(v, 0.f);
            C[(long)gm * N + gn] = v;
        }
    }
}

// ---------------------------------------------------------------------------
// pooled[b,f] = mean_l feats[b,l,f]
// ---------------------------------------------------------------------------
__global__ void pooled_kernel(const float* __restrict__ feats, float* __restrict__ pooled)
{
    int idx = blockIdx.x * blockDim.x + threadIdx.x;  // B_*FD_
    if (idx >= B_ * FD_) return;
    int b = idx / FD_, f = idx % FD_;
    const float* p = feats + (long)b * L_ * FD_ + f;
    float acc = 0.f;
    for (int l = 0; l < L_; l++) acc += p[(long)l * FD_];
    pooled[idx] = acc * (1.0f / L_);
}

// ---------------------------------------------------------------------------
// clf partials: out[b,n] += pooled[b, ks*256:(ks+1)*256] . W[..., n]
// grid.y = 8 k-splits; atomicAdd into zero-initialized out.
// ---------------------------------------------------------------------------
__global__ void clf_partial(const float* __restrict__ pooled, const float* __restrict__ W,
                            const float* __restrict__ bias, float* __restrict__ out)
{
    int i = blockIdx.x * blockDim.x + threadIdx.x;
    int ks = blockIdx.y;
    if (i >= B_ * NIMG_) return;
    int b = i / NIMG_, n = i % NIMG_;
    const float* p = pooled + (long)b * FD_ + ks * 256;
    const float* w = W + (long)(ks * 256) * NIMG_ + n;
    float acc = (ks == 0) ? bias[n] : 0.f;
    #pragma unroll 4
    for (int k = 0; k < 256; k++) acc = fmaf(p[k], w[(long)k * NIMG_], acc);
    atomicAdd(&out[i], acc);
}

// ---------------------------------------------------------------------------
// in-place row softmax, one wave per row
// ---------------------------------------------------------------------------
template<int NCOLS>
__global__ void softmax_rows(float* __restrict__ X, int rows)
{
    int gid = blockIdx.x * blockDim.x + threadIdx.x;
    int wave = gid >> 6, lane = gid & 63;
    if (wave >= rows) return;
    float* row = X + (long)wave * NCOLS;
    const int PER = (NCOLS + 63) / 64;
    float v[PER];
    float m = -1e30f;
    int cnt = 0;
    for (int k = lane; k < NCOLS; k += 64) { v[cnt] = row[k]; m = fmaxf(m, v[cnt]); cnt++; }
    #pragma unroll
    for (int off = 32; off; off >>= 1) m = fmaxf(m, __shfl_xor(m, off));
    float s = 0.f;
    for (int i = 0; i < cnt; i++) { v[i] = expf(v[i] - m); s += v[i]; }
    #pragma unroll
    for (int off = 32; off; off >>= 1) s += __shfl_xor(s, off);
    float inv = 1.f / s;
    cnt = 0;
    for (int k = lane; k < NCOLS; k += 64) row[k] = v[cnt++] * inv;
}

// ---------------------------------------------------------------------------
// h0_t[n*80 + b*5 + d] = h1[r,:] @ Wf2[:,d] + bf2[d]; r = b*N_+n (one wave/row)
// writes TRANSPOSED layout [N][B][D] for the recurrence.
// ---------------------------------------------------------------------------
__global__ void h0_kernel(const float* __restrict__ h1, const float* __restrict__ Wf2,
                          const float* __restrict__ bf2, float* __restrict__ h0t, int rows)
{
    int gid = blockIdx.x * blockDim.x + threadIdx.x;
    int wave = gid >> 6, lane = gid & 63;
    if (wave >= rows) return;
    const float* row = h1 + (long)wave * HD_;
    float acc[DD_] = {};
    for (int k = lane; k < HD_; k += 64) {
        float v = row[k];
        #pragma unroll
        for (int d = 0; d < DD_; d++) acc[d] = fmaf(v, Wf2[k * DD_ + d], acc[d]);
    }
    #pragma unroll
    for (int d = 0; d < DD_; d++)
        #pragma unroll
        for (int off = 32; off; off >>= 1) acc[d] += __shfl_down(acc[d], off);
    if (lane == 0) {
        int b = wave / N_, n = wave % N_;
        #pragma unroll
        for (int d = 0; d < DD_; d++)
            h0t[(long)n * (B_ * DD_) + b * DD_ + d] = acc[d] + bf2[d];
    }
}

// ---------------------------------------------------------------------------
// zero-fill
// ---------------------------------------------------------------------------
__global__ void zero_kernel(float* __restrict__ p, int n)
{
    int i = blockIdx.x * blockDim.x + threadIdx.x;
    if (i < n) p[i] = 0.f;
}

// ---------------------------------------------------------------------------
// Edge MLP as fused tile-GEMM: 64 edges x 256 units per block.
// layer1: et[e,:600] @ Wr1[600,256]  (et gathered from embed on the fly)
// epilogue: relu(+br1) . Wr2, cross-thread reduce, tanh(+br2), atomic scatter.
// 256 threads: x = t&15 (4 units x 4 col-blocks), y = t>>4 (4 edges each).
// ---------------------------------------------------------------------------
#define EPB 64
__global__ __launch_bounds__(256) void edge_gemm(
    const float* __restrict__ embed, const int* __restrict__ edges,
    const float* __restrict__ Wr1, const float* __restrict__ br1,
    const float* __restrict__ Wr2, const float* __restrict__ br2,
    float* __restrict__ prop)
{
    __shared__ float As[16][64];     // [kk][edge]
    __shared__ float Bs[16][256];    // [kk][unit]
    __shared__ int src[EPB], dst[EPB];
    __shared__ float part[EPB][17];
    int t = threadIdx.x;
    int e0 = blockIdx.x * EPB;
    if (t < EPB) {
        int e = e0 + t;
        src[t] = (e < E_) ? edges[e] : 0;
        dst[t] = (e < E_) ? edges[E_ + e] : 0;
    }
    __syncthreads();
    int x = t & 15, y = t >> 4;
    int eA = t >> 2;             // edge staged by this thread
    int kbase = (t & 3) * 4;     // kk base (4-aligned; 300 is 4-aligned so no straddle)
    float acc[4][16] = {};
    for (int k0 = 0; k0 < 600; k0 += 16) {
        // stage A (gather from embed)
        {
            int k4 = k0 + kbase;
            float4 v = make_float4(0.f, 0.f, 0.f, 0.f);
            if (k4 < 600) {
                int node = (k4 < 300) ? src[eA] : dst[eA];
                int c0 = (k4 < 300) ? k4 : k4 - 300;
                v = *(const float4*)(embed + (long)node * WD_ + c0);
            }
            As[kbase + 0][eA] = v.x;
            As[kbase + 1][eA] = v.y;
            As[kbase + 2][eA] = v.z;
            As[kbase + 3][eA] = v.w;
        }
        // stage B (Wr1 rows, coalesced float4)
        #pragma unroll
        for (int i = 0; i < 4; i++) {
            int f = i * 256 + t;
            int kk = f >> 6, uf = f & 63;
            float4 v = make_float4(0.f, 0.f, 0.f, 0.f);
            int gk = k0 + kk;
            if (gk < 600) v = *(const float4*)(Wr1 + (long)gk * 256 + uf * 4);
            *(float4*)&Bs[kk][uf * 4] = v;
        }
        __syncthreads();
        #pragma unroll
        for (int kk = 0; kk < 16; kk++) {
            float a[4];
            #pragma unroll
            for (int e = 0; e < 4; e++) a[e] = As[kk][y * 4 + e];
            #pragma unroll
            for (int cb = 0; cb < 4; cb++) {
                float b[4];
                #pragma unroll
                for (int j = 0; j < 4; j++) b[j] = Bs[kk][cb * 64 + x * 4 + j];
                #pragma unroll
                for (int e = 0; e < 4; e++)
                    #pragma unroll
                    for (int j = 0; j < 4; j++)
                        acc[e][cb * 4 + j] = fmaf(a[e], b[j], acc[e][cb * 4 + j]);
            }
        }
        __syncthreads();
    }
    // layer 2: relu(+br1) * Wr2, partial sums per edge
    float esum[4] = {};
    #pragma unroll
    for (int cb = 0; cb < 4; cb++)
        #pragma unroll
        for (int j = 0; j < 4; j++) {
            int u = cb * 64 + x * 4 + j;
            float b1 = br1[u], w2 = Wr2[u];
            #pragma unroll
            for (int e = 0; e < 4; e++)
                esum[e] = fmaf(fmaxf(acc[e][cb * 4 + j] + b1, 0.f), w2, esum[e]);
        }
    #pragma unroll
    for (int e = 0; e < 4; e++) part[y * 4 + e][x] = esum[e];
    __syncthreads();
    if (t < EPB) {
        float s = 0.f;
        #pragma unroll
        for (int i = 0; i < 16; i++) s += part[t][i];
        if (e0 + t < E_)
            atomicAdd(&prop[(long)src[t] * N_ + dst[t]], tanhf(s + br2[0]));
    }
}

// ---------------------------------------------------------------------------
// Fused recurrence step on TRANSPOSED hidden H[N][B*D=80]:
//   msg = tanh(prop @ Hin); Hout = GRU(msg, Hin)
// Block: 32 n-rows, 256 threads (x=t&15 -> batch b, y=t>>4 -> 2 n each).
// Ping-pong Hin/Hout removes intra-step races.
// ---------------------------------------------------------------------------
__global__ __launch_bounds__(256) void step_kernel(
    const float* __restrict__ prop, const float* __restrict__ Hin,
    float* __restrict__ Hout,
    const float* __restrict__ W_ih, const float* __restrict__ b_ih,
    const float* __restrict__ W_hh, const float* __restrict__ b_hh)
{
    __shared__ float As[16][34];   // [kk][nn] prop tile
    __shared__ float Bs[16][80];   // [kk][b*5+d] Hin tile
    int t = threadIdx.x;
    int x = t & 15, y = t >> 4;
    int n0 = blockIdx.x * 32;
    float acc[2][5] = {};
    for (int k0 = 0; k0 < N_; k0 += 16) {
        {
            int id = t * 2;
            int nn = id >> 4, kb = id & 15;
            int gn = n0 + nn, gk = k0 + kb;
            float2 v = make_float2(0.f, 0.f);
            if (gn < N_) {
                if (gk + 1 < N_)      v = *(const float2*)(prop + (long)gn * N_ + gk);
                else if (gk < N_)     v.x = prop[(long)gn * N_ + gk];
            }
            As[kb][nn] = v.x;
            As[kb + 1][nn] = v.y;
        }
        #pragma unroll
        for (int i = 0; i < 5; i++) {
            int id = i * 256 + t;
            int g = k0 * 80 + id;
            Bs[id / 80][id % 80] = (g < N_ * 80) ? Hin[g] : 0.f;
        }
        __syncthreads();
        #pragma unroll
        for (int kk = 0; kk < 16; kk++) {
            float a0 = As[kk][y * 2], a1 = As[kk][y * 2 + 1];
            #pragma unroll
            for (int j = 0; j < 5; j++) {
                float b = Bs[kk][x * 5 + j];
                acc[0][j] = fmaf(a0, b, acc[0][j]);
                acc[1][j] = fmaf(a1, b, acc[1][j]);
            }
        }
        __syncthreads();
    }
    #pragma unroll
    for (int i = 0; i < 2; i++) {
        int n = n0 + y * 2 + i;
        if (n >= N_) continue;
        float xv[DD_], h[DD_];
        #pragma unroll
        for (int j = 0; j < DD_; j++) {
            xv[j] = tanhf(acc[i][j]);
            h[j] = Hin[(long)n * 80 + x * DD_ + j];
        }
        float gi[3 * DD_], gh[3 * DD_];
        #pragma unroll
        for (int g = 0; g < 3 * DD_; g++) {
            float a = b_ih[g], c = b_hh[g];
            #pragma unroll
            for (int k = 0; k < DD_; k++) {
                a = fmaf(xv[k], W_ih[g * DD_ + k], a);
                c = fmaf(h[k], W_hh[g * DD_ + k], c);
            }
            gi[g] = a; gh[g] = c;
        }
        #pragma unroll
        for (int j = 0; j < DD_; j++) {
            float rr = 1.f / (1.f + expf(-(gi[j] + gh[j])));
            float zz = 1.f / (1.f + expf(-(gi[DD_ + j] + gh[DD_ + j])));
            float nn2 = tanhf(gi[2 * DD_ + j] + rr * gh[2 * DD_ + j]);
            Hout[(long)n * 80 + x * DD_ + j] = (1.f - zz) * nn2 + zz * h[j];
        }
    }
}

// ---------------------------------------------------------------------------
// logits[r] = relu(h_t[n,b,:] @ Wo1 + bo1) @ Wo2 + bo2 ; r = b*N_+n (wave/row)
// reads TRANSPOSED hidden.
// ---------------------------------------------------------------------------
__global__ void out_kernel(const float* __restrict__ ht, const float* __restrict__ Wo1,
                           const float* __restrict__ bo1, const float* __restrict__ Wo2,
                           const float* __restrict__ bo2, float* __restrict__ logits, int rows)
{
    int gid = blockIdx.x * blockDim.x + threadIdx.x;
    int wave = gid >> 6, lane = gid & 63;
    if (wave >= rows) return;
    int b = wave / N_, n = wave % N_;
    float x[DD_];
    #pragma unroll
    for (int i = 0; i < DD_; i++) x[i] = ht[(long)n * (B_ * DD_) + b * DD_ + i];
    float acc = 0.f;
    for (int j = lane; j < HD_; j += 64) {
        float h = bo1[j];
        #pragma unroll
        for (int d = 0; d < DD_; d++) h = fmaf(x[d], Wo1[d * HD_ + j], h);
        h = fmaxf(h, 0.f);
        acc = fmaf(h, Wo2[j], acc);
    }
    #pragma unroll
    for (int off = 32; off; off >>= 1) acc += __shfl_down(acc, off);
    if (lane == 0) logits[wave] = acc + bo2[0];
}

// ---------------------------------------------------------------------------
extern "C" void kernel_launch(void* const* d_in, const int* in_sizes, int n_in,
                              void* d_out, int out_size, void* d_ws, size_t ws_size,
                              hipStream_t stream)
{
    const float* feats   = (const float*)d_in[0];
    const float* embed   = (const float*)d_in[1];
    const int*   edges   = (const int*)  d_in[2];
    const float* W_key   = (const float*)d_in[3];
    const float* b_key   = (const float*)d_in[4];
    const float* W_query = (const float*)d_in[5];
    const float* b_query = (const float*)d_in[6];
    const float* Wf1     = (const float*)d_in[7];
    const float* bf1     = (const float*)d_in[8];
    const float* Wf2     = (const float*)d_in[9];
    const float* bf2     = (const float*)d_in[10];
    const float* Wr1     = (const float*)d_in[11];
    const float* br1     = (const float*)d_in[12];
    const float* Wr2     = (const float*)d_in[13];
    const float* br2     = (const float*)d_in[14];
    const float* Wo1     = (const float*)d_in[15];
    const float* bo1     = (const float*)d_in[16];
    const float* Wo2     = (const float*)d_in[17];
    const float* bo2     = (const float*)d_in[18];
    const float* W_ih    = (const float*)d_in[19];
    const float* b_ih    = (const float*)d_in[20];
    const float* W_hh    = (const float*)d_in[21];
    const float* b_hh    = (const float*)d_in[22];
    const float* W_clf   = (const float*)d_in[23];
    const float* b_clf   = (const float*)d_in[24];

    float* out_logits = (float*)d_out;          // [16,1000]
    float* out_attn   = out_logits + B_ * N_;   // [16,1000,196]
    float* out_img    = out_attn + (long)B_ * N_ * L_;  // [16,1000]

    float* ws = (float*)d_ws;
    float* pooled  = ws;  ws += B_ * FD_;            // 32768
    float* keys    = ws;  ws += B_ * L_ * HD_;       // 1605632
    float* F1      = ws;  ws += B_ * L_ * HD_;       // 1605632
    float* queries = ws;  ws += N_ * HD_;            // 512000
    float* h1      = ws;  ws += (long)B_ * N_ * HD_; // 8192000
    float* prop    = ws;  ws += N_ * N_;             // 1000000
    float* Ht0     = ws;  ws += N_ * B_ * DD_;       // 80000
    float* Ht1     = ws;  ws += N_ * B_ * DD_;       // 80000

    // --- imagenet classifier path (split-K + atomics) ---
    pooled_kernel<<<(B_ * FD_ + 255) / 256, 256, 0, stream>>>(feats, pooled);
    zero_kernel<<<(B_ * NIMG_ + 255) / 256, 256, 0, stream>>>(out_img, B_ * NIMG_);
    {
        dim3 g((B_ * NIMG_ + 255) / 256, FD_ / 256);
        clf_partial<<<g, 256, 0, stream>>>(pooled, W_clf, b_clf, out_img);
    }
    softmax_rows<NIMG_><<<(B_ * 64 + 255) / 256, 256, 0, stream>>>(out_img, B_);

    // --- prop matrix ---
    zero_kernel<<<(N_ * N_ + 255) / 256, 256, 0, stream>>>(prop, N_ * N_);
    edge_gemm<<<(E_ + EPB - 1) / EPB, 256, 0, stream>>>(embed, edges, Wr1, br1, Wr2, br2, prop);

    // --- attention path ---
    // keys = feats @ W_key + b_key   [3136, 512]
    {
        dim3 g(HD_ / 64, (B_ * L_ + 63) / 64, 1);
        gemm_k<false, false><<<g, 256, 0, stream>>>(feats, W_key, b_key, keys,
                                                    B_ * L_, HD_, FD_, 0, 0, 0);
    }
    // F1 = feats @ Wf1 (no bias)    [3136, 512]
    {
        dim3 g(HD_ / 64, (B_ * L_ + 63) / 64, 1);
        gemm_k<false, false><<<g, 256, 0, stream>>>(feats, Wf1, nullptr, F1,
                                                    B_ * L_, HD_, FD_, 0, 0, 0);
    }
    // queries = embed @ W_query + b_query  [1000, 512]
    {
        dim3 g(HD_ / 64, (N_ + 63) / 64, 1);
        gemm_k<false, false><<<g, 256, 0, stream>>>(embed, W_query, b_query, queries,
                                                    N_, HD_, WD_, 0, 0, 0);
    }
    // scores[b] = queries @ keys[b]^T -> out_attn   [16][1000,196]
    {
        dim3 g((L_ + 63) / 64, (N_ + 63) / 64, B_);
        gemm_k<true, false><<<g, 256, 0, stream>>>(queries, keys, nullptr, out_attn,
                                                   N_, L_, HD_,
                                                   0, (long)L_ * HD_, (long)N_ * L_);
    }
    softmax_rows<L_><<<(B_ * N_ * 64 + 255) / 256, 256, 0, stream>>>(out_attn, B_ * N_);

    // h1 = relu(attn @ F1 + bf1)   [16][1000,512]
    {
        dim3 g(HD_ / 64, (N_ + 63) / 64, B_);
        gemm_k<false, true><<<g, 256, 0, stream>>>(out_attn, F1, bf1, h1,
                                                   N_, HD_, L_,
                                                   (long)N_ * L_, (long)L_ * HD_, (long)N_ * HD_);
    }
    // hidden (transposed [N][B][D]) = h1 @ Wf2 + bf2
    h0_kernel<<<(B_ * N_ * 64 + 255) / 256, 256, 0, stream>>>(h1, Wf2, bf2, Ht0, B_ * N_);

    // --- recurrence: 5 fused steps, ping-pong ---
    {
        float* hin = Ht0;
        float* hout = Ht1;
        for (int step = 0; step < TMAX_; step++) {
            step_kernel<<<(N_ + 31) / 32, 256, 0, stream>>>(prop, hin, hout,
                                                            W_ih, b_ih, W_hh, b_hh);
            float* tmp = hin; hin = hout; hout = tmp;
        }
        // after 5 steps, result is in `hin` (Ht1)
        out_kernel<<<(B_ * N_ * 64 + 255) / 256, 256, 0, stream>>>(hin, Wo1, bo1, Wo2, bo2,
                                                                   out_logits, B_ * N_);
    }
}

// Round 3
// 1497.519 us; speedup vs baseline: 1.5110x; 1.4444x over previous
//
#include <hip/hip_runtime.h>
#include <hip/hip_bf16.h>
#include <math.h>

// Problem constants
#define B_   16
#define L_   196
#define FD_  2048
#define N_   1000
#define WD_  300
#define HD_  512
#define DD_  5
#define E_   50000
#define TMAX_ 5
#define NIMG_ 1000

typedef __attribute__((ext_vector_type(8))) short bf16x8;
typedef __attribute__((ext_vector_type(4))) float f32x4;

__device__ __forceinline__ short bf_hi(float x) {
    unsigned u = __float_as_uint(x);
    unsigned r = u + 0x7fffu + ((u >> 16) & 1u);
    return (short)(r >> 16);
}
__device__ __forceinline__ float bf2f_(short s) {
    return __uint_as_float(((unsigned)(unsigned short)s) << 16);
}

// ---------------------------------------------------------------------------
// Transpose + convert: in fp32 [K][N] -> outH (and optionally outL) bf16 [N][K]
// ---------------------------------------------------------------------------
__global__ __launch_bounds__(256) void transconv(
    const float* __restrict__ in, short* __restrict__ outH, short* __restrict__ outL,
    int K, int N)
{
    __shared__ float tile[32][33];
    int k0 = blockIdx.x * 32, n0 = blockIdx.y * 32;
    int t = threadIdx.x;
    int tr = t >> 5, tc = t & 31;
    #pragma unroll
    for (int i = 0; i < 4; i++) {
        int k = k0 + tr + i * 8, n = n0 + tc;
        tile[tr + i * 8][tc] = (k < K && n < N) ? in[(long)k * N + n] : 0.f;
    }
    __syncthreads();
    #pragma unroll
    for (int i = 0; i < 4; i++) {
        int n = n0 + tr + i * 8, k = k0 + tc;
        if (n < N && k < K) {
            float x = tile[tc][tr + i * 8];
            short hi = bf_hi(x);
            outH[(long)n * K + k] = hi;
            if (outL) outL[(long)n * K + k] = bf_hi(x - bf2f_(hi));
        }
    }
}

// elementwise fp32 -> bf16 (hi plane only)
__global__ void conv_bf16(const float* __restrict__ in, short* __restrict__ out, int n)
{
    int i = blockIdx.x * blockDim.x + threadIdx.x;
    if (i < n) out[i] = bf_hi(in[i]);
}

// ---------------------------------------------------------------------------
// MFMA GEMM: C = act(A @ B^T + bias), A fp32 [M][K] (inline bf16 convert),
// B given as [N][K] bf16 planes (hi, optional lo). 64x64 tile, 128 threads
// (2 waves, each 32x64), BK=32, 16x16x32 bf16 MFMA.
// SPLIT: 3 segments (Ahi*Bhi + Alo*Bhi + Ahi*Blo) for ~fp32 accuracy.
// OUTMODE: 0=fp32, 1=bf16 hi/lo planes, 2=transposed bf16 [b][N][196], 3=bf16.
// ---------------------------------------------------------------------------
#define OUT_F32   0
#define OUT_SPLIT 1
#define OUT_TRANS 2
#define OUT_BF16  3

template<int OUTMODE, bool SPLIT, bool RELU>
__global__ __launch_bounds__(128) void mm_mfma(
    const float* __restrict__ A, const short* __restrict__ Bh,
    const short* __restrict__ Bl, const float* __restrict__ bias,
    void* __restrict__ C0, void* __restrict__ C1,
    int M, int N, int K, long sA, long sB, long sC)
{
    __shared__ short As[64][40];
    __shared__ short Bs[64][40];
    int z = blockIdx.z;
    A += (long)z * sA;
    Bh += (long)z * sB;
    if (Bl) Bl += (long)z * sB;
    int t = threadIdx.x;
    int lane = t & 63, w = t >> 6;
    int q = lane >> 4, r = lane & 15;
    int row0 = blockIdx.y * 64, col0 = blockIdx.x * 64;
    f32x4 zero4 = {0.f, 0.f, 0.f, 0.f};
    f32x4 acc[2][4];
    #pragma unroll
    for (int i = 0; i < 2; i++)
        #pragma unroll
        for (int j = 0; j < 4; j++) acc[i][j] = zero4;

    int Ksteps = (K + 31) >> 5;
    int nseg = SPLIT ? 3 : 1;
    for (int seg = 0; seg < nseg; seg++) {
        for (int ks = 0; ks < Ksteps; ks++) {
            int k0 = ks * 32;
            // --- stage A (64 x 32), fp32 -> bf16 (hi or lo per segment)
            {
                int arow = t >> 1, kc = (t & 1) * 16;
                int gm = row0 + arow;
                const float* ap = A + (long)gm * K + k0 + kc;
                short tmp[16];
                bool lo = SPLIT && (seg == 1);
                if (gm < M && k0 + 32 <= K) {
                    #pragma unroll
                    for (int u4 = 0; u4 < 4; u4++) {
                        float4 v = *(const float4*)(ap + u4 * 4);
                        float xs[4] = {v.x, v.y, v.z, v.w};
                        #pragma unroll
                        for (int j = 0; j < 4; j++) {
                            short hi = bf_hi(xs[j]);
                            tmp[u4 * 4 + j] = lo ? bf_hi(xs[j] - bf2f_(hi)) : hi;
                        }
                    }
                } else {
                    #pragma unroll
                    for (int j = 0; j < 16; j++) {
                        int gk = k0 + kc + j;
                        float x = (gm < M && gk < K) ? ap[j] : 0.f;
                        short hi = bf_hi(x);
                        tmp[j] = lo ? bf_hi(x - bf2f_(hi)) : hi;
                    }
                }
                *(int4*)&As[arow][kc] = *(int4*)&tmp[0];
                *(int4*)&As[arow][kc + 8] = *(int4*)&tmp[8];
            }
            // --- stage B (64 x 32) from bf16 [N][K]
            {
                int brow = t >> 1, kc = (t & 1) * 16;
                int gn = col0 + brow;
                const short* Bp = (SPLIT && seg == 2) ? Bl : Bh;
                const short* bp = Bp + (long)gn * K + k0 + kc;
                short tmp[16];
                if (gn < N && k0 + 32 <= K) {
                    #pragma unroll
                    for (int u2 = 0; u2 < 4; u2++)
                        *(int2*)&tmp[u2 * 4] = *(const int2*)(bp + u2 * 4);
                } else {
                    #pragma unroll
                    for (int j = 0; j < 16; j++) {
                        int gk = k0 + kc + j;
                        tmp[j] = (gn < N && gk < K) ? bp[j] : (short)0;
                    }
                }
                *(int4*)&Bs[brow][kc] = *(int4*)&tmp[0];
                *(int4*)&Bs[brow][kc + 8] = *(int4*)&tmp[8];
            }
            __syncthreads();
            bf16x8 af0 = *(const bf16x8*)&As[w * 32 + r][q * 8];
            bf16x8 af1 = *(const bf16x8*)&As[w * 32 + 16 + r][q * 8];
            #pragma unroll
            for (int ct = 0; ct < 4; ct++) {
                bf16x8 bfr = *(const bf16x8*)&Bs[ct * 16 + r][q * 8];
                acc[0][ct] = __builtin_amdgcn_mfma_f32_16x16x32_bf16(af0, bfr, acc[0][ct], 0, 0, 0);
                acc[1][ct] = __builtin_amdgcn_mfma_f32_16x16x32_bf16(af1, bfr, acc[1][ct], 0, 0, 0);
            }
            __syncthreads();
        }
    }
    // --- epilogue
    #pragma unroll
    for (int i = 0; i < 2; i++) {
        #pragma unroll
        for (int ct = 0; ct < 4; ct++) {
            #pragma unroll
            for (int reg = 0; reg < 4; reg++) {
                int m = row0 + w * 32 + i * 16 + q * 4 + reg;
                int n = col0 + ct * 16 + r;
                if (m >= M || n >= N) continue;
                float v = acc[i][ct][reg];
                if (bias) v += bias[n];
                if (RELU) v = fmaxf(v, 0.f);
                long idx = (long)z * sC + (long)m * N + n;
                if (OUTMODE == OUT_F32) {
                    ((float*)C0)[idx] = v;
                } else if (OUTMODE == OUT_SPLIT) {
                    short hi = bf_hi(v);
                    ((short*)C0)[idx] = hi;
                    ((short*)C1)[idx] = bf_hi(v - bf2f_(hi));
                } else if (OUTMODE == OUT_BF16) {
                    ((short*)C0)[idx] = bf_hi(v);
                } else { // OUT_TRANS: [b][N][196] from m = b*196 + l
                    int b = m / 196, l = m - b * 196;
                    ((short*)C0)[((long)b * N + n) * 196 + l] = bf_hi(v);
                }
            }
        }
    }
}

// ---------------------------------------------------------------------------
// Edge MLP via MFMA: 64 edges x 256 units/block, K=600 (pad 608).
// A gathered from embedH (bf16 [1000][300]); B = Wr1T bf16 [256][600].
// Epilogue: relu(+br1).Wr2 reduce -> tanh(+br2) -> atomic scatter to prop.
// ---------------------------------------------------------------------------
__global__ __launch_bounds__(256) void edge_mfma(
    const short* __restrict__ embedH, const int* __restrict__ edges,
    const short* __restrict__ Wr1T, const float* __restrict__ br1,
    const float* __restrict__ Wr2, const float* __restrict__ br2,
    float* __restrict__ prop)
{
    __shared__ short As[64][40];
    __shared__ short Bs[256][40];
    __shared__ int src[64], dst[64];
    __shared__ float part[64][5];
    int t = threadIdx.x;
    int e0 = blockIdx.x * 64;
    if (t < 64) {
        int e = e0 + t;
        src[t] = (e < E_) ? edges[e] : 0;
        dst[t] = (e < E_) ? edges[E_ + e] : 0;
    }
    __syncthreads();
    int lane = t & 63, w = t >> 6, q = lane >> 4, r = lane & 15;
    f32x4 zero4 = {0.f, 0.f, 0.f, 0.f};
    f32x4 acc[4][4];
    #pragma unroll
    for (int i = 0; i < 4; i++)
        #pragma unroll
        for (int j = 0; j < 4; j++) acc[i][j] = zero4;

    for (int ks = 0; ks < 19; ks++) {
        int k0 = ks * 32;
        // A gather (64 x 32)
        {
            int arow = t >> 2, kc = (t & 3) * 8;
            int gk0 = k0 + kc;
            int sn = src[arow], dn = dst[arow];
            short tmp[8];
            if (gk0 + 8 <= 300) {
                const short* p = embedH + (long)sn * 300 + gk0;
                *(int2*)&tmp[0] = *(const int2*)p;
                *(int2*)&tmp[4] = *(const int2*)(p + 4);
            } else if (gk0 >= 300 && gk0 + 8 <= 600) {
                const short* p = embedH + (long)dn * 300 + (gk0 - 300);
                *(int2*)&tmp[0] = *(const int2*)p;
                *(int2*)&tmp[4] = *(const int2*)(p + 4);
            } else {
                #pragma unroll
                for (int j = 0; j < 8; j++) {
                    int gk = gk0 + j;
                    short v = 0;
                    if (gk < 300) v = embedH[(long)sn * 300 + gk];
                    else if (gk < 600) v = embedH[(long)dn * 300 + gk - 300];
                    tmp[j] = v;
                }
            }
            *(int4*)&As[arow][kc] = *(int4*)&tmp[0];
        }
        // B stage (256 x 32)
        #pragma unroll
        for (int i = 0; i < 4; i++) {
            int n = i * 64 + (t >> 2), kc = (t & 3) * 8;
            int gk0 = k0 + kc;
            short tmp[8];
            if (gk0 + 8 <= 600) {
                const short* p = Wr1T + (long)n * 600 + gk0;
                *(int2*)&tmp[0] = *(const int2*)p;
                *(int2*)&tmp[4] = *(const int2*)(p + 4);
            } else {
                #pragma unroll
                for (int j = 0; j < 8; j++) tmp[j] = 0;
            }
            *(int4*)&Bs[n][kc] = *(int4*)&tmp[0];
        }
        __syncthreads();
        bf16x8 af[4], bfr[4];
        #pragma unroll
        for (int rt = 0; rt < 4; rt++) af[rt] = *(const bf16x8*)&As[rt * 16 + r][q * 8];
        #pragma unroll
        for (int ct = 0; ct < 4; ct++) bfr[ct] = *(const bf16x8*)&Bs[w * 64 + ct * 16 + r][q * 8];
        #pragma unroll
        for (int rt = 0; rt < 4; rt++)
            #pragma unroll
            for (int ct = 0; ct < 4; ct++)
                acc[rt][ct] = __builtin_amdgcn_mfma_f32_16x16x32_bf16(af[rt], bfr[ct], acc[rt][ct], 0, 0, 0);
        __syncthreads();
    }
    // layer-2 epilogue
    float b1v[4], w2v[4];
    #pragma unroll
    for (int ct = 0; ct < 4; ct++) {
        int u = w * 64 + ct * 16 + r;
        b1v[ct] = br1[u];
        w2v[ct] = Wr2[u];
    }
    #pragma unroll
    for (int rt = 0; rt < 4; rt++) {
        #pragma unroll
        for (int reg = 0; reg < 4; reg++) {
            float s = 0.f;
            #pragma unroll
            for (int ct = 0; ct < 4; ct++)
                s = fmaf(fmaxf(acc[rt][ct][reg] + b1v[ct], 0.f), w2v[ct], s);
            s += __shfl_xor(s, 1);
            s += __shfl_xor(s, 2);
            s += __shfl_xor(s, 4);
            s += __shfl_xor(s, 8);
            if (r == 0) part[rt * 16 + q * 4 + reg][w] = s;
        }
    }
    __syncthreads();
    if (t < 64 && e0 + t < E_) {
        float s = part[t][0] + part[t][1] + part[t][2] + part[t][3];
        atomicAdd(&prop[(long)src[t] * N_ + dst[t]], tanhf(s + br2[0]));
    }
}

// ---------------------------------------------------------------------------
__global__ void pooled_kernel(const float* __restrict__ feats, float* __restrict__ pooled)
{
    int idx = blockIdx.x * blockDim.x + threadIdx.x;
    if (idx >= B_ * FD_) return;
    int b = idx / FD_, f = idx % FD_;
    const float* p = feats + (long)b * L_ * FD_ + f;
    float acc = 0.f;
    for (int l = 0; l < L_; l++) acc += p[(long)l * FD_];
    pooled[idx] = acc * (1.0f / L_);
}

__global__ void clf_partial(const float* __restrict__ pooled, const float* __restrict__ W,
                            const float* __restrict__ bias, float* __restrict__ out)
{
    int i = blockIdx.x * blockDim.x + threadIdx.x;
    int ks = blockIdx.y;
    if (i >= B_ * NIMG_) return;
    int b = i / NIMG_, n = i % NIMG_;
    const float* p = pooled + (long)b * FD_ + ks * 256;
    const float* w = W + (long)(ks * 256) * NIMG_ + n;
    float acc = (ks == 0) ? bias[n] : 0.f;
    #pragma unroll 4
    for (int k = 0; k < 256; k++) acc = fmaf(p[k], w[(long)k * NIMG_], acc);
    atomicAdd(&out[i], acc);
}

template<int NCOLS>
__global__ void softmax_rows(float* __restrict__ X, int rows)
{
    int gid = blockIdx.x * blockDim.x + threadIdx.x;
    int wave = gid >> 6, lane = gid & 63;
    if (wave >= rows) return;
    float* row = X + (long)wave * NCOLS;
    const int PER = (NCOLS + 63) / 64;
    float v[PER];
    float m = -1e30f;
    int cnt = 0;
    for (int k = lane; k < NCOLS; k += 64) { v[cnt] = row[k]; m = fmaxf(m, v[cnt]); cnt++; }
    #pragma unroll
    for (int off = 32; off; off >>= 1) m = fmaxf(m, __shfl_xor(m, off));
    float s = 0.f;
    for (int i = 0; i < cnt; i++) { v[i] = expf(v[i] - m); s += v[i]; }
    #pragma unroll
    for (int off = 32; off; off >>= 1) s += __shfl_xor(s, off);
    float inv = 1.f / s;
    cnt = 0;
    for (int k = lane; k < NCOLS; k += 64) row[k] = v[cnt++] * inv;
}

// h0: reads h1 (bf16 [r][512]), writes transposed [N][B][D]
__global__ void h0_kernel(const short* __restrict__ h1, const float* __restrict__ Wf2,
                          const float* __restrict__ bf2, float* __restrict__ h0t, int rows)
{
    int gid = blockIdx.x * blockDim.x + threadIdx.x;
    int wave = gid >> 6, lane = gid & 63;
    if (wave >= rows) return;
    const short* row = h1 + (long)wave * HD_;
    float acc[DD_] = {};
    for (int k = lane; k < HD_; k += 64) {
        float v = bf2f_(row[k]);
        #pragma unroll
        for (int d = 0; d < DD_; d++) acc[d] = fmaf(v, Wf2[k * DD_ + d], acc[d]);
    }
    #pragma unroll
    for (int d = 0; d < DD_; d++)
        #pragma unroll
        for (int off = 32; off; off >>= 1) acc[d] += __shfl_down(acc[d], off);
    if (lane == 0) {
        int b = wave / N_, n = wave % N_;
        #pragma unroll
        for (int d = 0; d < DD_; d++)
            h0t[(long)n * (B_ * DD_) + b * DD_ + d] = acc[d] + bf2[d];
    }
}

__global__ void zero_kernel(float* __restrict__ p, int n)
{
    int i = blockIdx.x * blockDim.x + threadIdx.x;
    if (i < n) p[i] = 0.f;
}

// Fused recurrence step on transposed hidden H[N][B*D=80]
__global__ __launch_bounds__(256) void step_kernel(
    const float* __restrict__ prop, const float* __restrict__ Hin,
    float* __restrict__ Hout,
    const float* __restrict__ W_ih, const float* __restrict__ b_ih,
    const float* __restrict__ W_hh, const float* __restrict__ b_hh)
{
    __shared__ float As[16][34];
    __shared__ float Bs[16][80];
    int t = threadIdx.x;
    int x = t & 15, y = t >> 4;
    int n0 = blockIdx.x * 32;
    float acc[2][5] = {};
    for (int k0 = 0; k0 < N_; k0 += 16) {
        {
            int id = t * 2;
            int nn = id >> 4, kb = id & 15;
            int gn = n0 + nn, gk = k0 + kb;
            float2 v = make_float2(0.f, 0.f);
            if (gn < N_) {
                if (gk + 1 < N_)      v = *(const float2*)(prop + (long)gn * N_ + gk);
                else if (gk < N_)     v.x = prop[(long)gn * N_ + gk];
            }
            As[kb][nn] = v.x;
            As[kb + 1][nn] = v.y;
        }
        #pragma unroll
        for (int i = 0; i < 5; i++) {
            int id = i * 256 + t;
            int g = k0 * 80 + id;
            Bs[id / 80][id % 80] = (g < N_ * 80) ? Hin[g] : 0.f;
        }
        __syncthreads();
        #pragma unroll
        for (int kk = 0; kk < 16; kk++) {
            float a0 = As[kk][y * 2], a1 = As[kk][y * 2 + 1];
            #pragma unroll
            for (int j = 0; j < 5; j++) {
                float b = Bs[kk][x * 5 + j];
                acc[0][j] = fmaf(a0, b, acc[0][j]);
                acc[1][j] = fmaf(a1, b, acc[1][j]);
            }
        }
        __syncthreads();
    }
    #pragma unroll
    for (int i = 0; i < 2; i++) {
        int n = n0 + y * 2 + i;
        if (n >= N_) continue;
        float xv[DD_], h[DD_];
        #pragma unroll
        for (int j = 0; j < DD_; j++) {
            xv[j] = tanhf(acc[i][j]);
            h[j] = Hin[(long)n * 80 + x * DD_ + j];
        }
        float gi[3 * DD_], gh[3 * DD_];
        #pragma unroll
        for (int g = 0; g < 3 * DD_; g++) {
            float a = b_ih[g], c = b_hh[g];
            #pragma unroll
            for (int k = 0; k < DD_; k++) {
                a = fmaf(xv[k], W_ih[g * DD_ + k], a);
                c = fmaf(h[k], W_hh[g * DD_ + k], c);
            }
            gi[g] = a; gh[g] = c;
        }
        #pragma unroll
        for (int j = 0; j < DD_; j++) {
            float rr = 1.f / (1.f + expf(-(gi[j] + gh[j])));
            float zz = 1.f / (1.f + expf(-(gi[DD_ + j] + gh[DD_ + j])));
            float nn2 = tanhf(gi[2 * DD_ + j] + rr * gh[2 * DD_ + j]);
            Hout[(long)n * 80 + x * DD_ + j] = (1.f - zz) * nn2 + zz * h[j];
        }
    }
}

__global__ void out_kernel(const float* __restrict__ ht, const float* __restrict__ Wo1,
                           const float* __restrict__ bo1, const float* __restrict__ Wo2,
                           const float* __restrict__ bo2, float* __restrict__ logits, int rows)
{
    int gid = blockIdx.x * blockDim.x + threadIdx.x;
    int wave = gid >> 6, lane = gid & 63;
    if (wave >= rows) return;
    int b = wave / N_, n = wave % N_;
    float x[DD_];
    #pragma unroll
    for (int i = 0; i < DD_; i++) x[i] = ht[(long)n * (B_ * DD_) + b * DD_ + i];
    float acc = 0.f;
    for (int j = lane; j < HD_; j += 64) {
        float h = bo1[j];
        #pragma unroll
        for (int d = 0; d < DD_; d++) h = fmaf(x[d], Wo1[d * HD_ + j], h);
        h = fmaxf(h, 0.f);
        acc = fmaf(h, Wo2[j], acc);
    }
    #pragma unroll
    for (int off = 32; off; off >>= 1) acc += __shfl_down(acc, off);
    if (lane == 0) logits[wave] = acc + bo2[0];
}

// ---------------------------------------------------------------------------
extern "C" void kernel_launch(void* const* d_in, const int* in_sizes, int n_in,
                              void* d_out, int out_size, void* d_ws, size_t ws_size,
                              hipStream_t stream)
{
    const float* feats   = (const float*)d_in[0];
    const float* embed   = (const float*)d_in[1];
    const int*   edges   = (const int*)  d_in[2];
    const float* W_key   = (const float*)d_in[3];
    const float* b_key   = (const float*)d_in[4];
    const float* W_query = (const float*)d_in[5];
    const float* b_query = (const float*)d_in[6];
    const float* Wf1     = (const float*)d_in[7];
    const float* bf1     = (const float*)d_in[8];
    const float* Wf2     = (const float*)d_in[9];
    const float* bf2     = (const float*)d_in[10];
    const float* Wr1     = (const float*)d_in[11];
    const float* br1     = (const float*)d_in[12];
    const float* Wr2     = (const float*)d_in[13];
    const float* br2     = (const float*)d_in[14];
    const float* Wo1     = (const float*)d_in[15];
    const float* bo1     = (const float*)d_in[16];
    const float* Wo2     = (const float*)d_in[17];
    const float* bo2     = (const float*)d_in[18];
    const float* W_ih    = (const float*)d_in[19];
    const float* b_ih    = (const float*)d_in[20];
    const float* W_hh    = (const float*)d_in[21];
    const float* b_hh    = (const float*)d_in[22];
    const float* W_clf   = (const float*)d_in[23];
    const float* b_clf   = (const float*)d_in[24];

    float* out_logits = (float*)d_out;
    float* out_attn   = out_logits + B_ * N_;
    float* out_img    = out_attn + (long)B_ * N_ * L_;

    char* p = (char*)d_ws;
    auto alloc = [&](size_t bytes) { void* r = (void*)p; p += (bytes + 255) & ~(size_t)255; return r; };
    float* pooled  = (float*)alloc((size_t)B_ * FD_ * 4);
    short* WkTh    = (short*)alloc((size_t)HD_ * FD_ * 2);
    short* WkTl    = (short*)alloc((size_t)HD_ * FD_ * 2);
    short* WqTh    = (short*)alloc((size_t)HD_ * WD_ * 2);
    short* WqTl    = (short*)alloc((size_t)HD_ * WD_ * 2);
    short* Wf1T    = (short*)alloc((size_t)HD_ * FD_ * 2);
    short* Wr1T    = (short*)alloc((size_t)256 * 600 * 2);
    short* embH    = (short*)alloc((size_t)N_ * WD_ * 2);
    short* keysH   = (short*)alloc((size_t)B_ * L_ * HD_ * 2);
    short* keysL   = (short*)alloc((size_t)B_ * L_ * HD_ * 2);
    float* queries = (float*)alloc((size_t)N_ * HD_ * 4);
    short* F1T     = (short*)alloc((size_t)B_ * HD_ * L_ * 2);
    short* h1b     = (short*)alloc((size_t)B_ * N_ * HD_ * 2);
    float* prop    = (float*)alloc((size_t)N_ * N_ * 4);
    float* Ht0     = (float*)alloc((size_t)N_ * B_ * DD_ * 4);
    float* Ht1     = (float*)alloc((size_t)N_ * B_ * DD_ * 4);

    // --- imagenet classifier path ---
    pooled_kernel<<<(B_ * FD_ + 255) / 256, 256, 0, stream>>>(feats, pooled);
    zero_kernel<<<(B_ * NIMG_ + 255) / 256, 256, 0, stream>>>(out_img, B_ * NIMG_);
    {
        dim3 g((B_ * NIMG_ + 255) / 256, FD_ / 256);
        clf_partial<<<g, 256, 0, stream>>>(pooled, W_clf, b_clf, out_img);
    }
    softmax_rows<NIMG_><<<(B_ * 64 + 255) / 256, 256, 0, stream>>>(out_img, B_);

    // --- weight pre-transpose/convert ---
    {
        dim3 g((FD_ + 31) / 32, (HD_ + 31) / 32);
        transconv<<<g, 256, 0, stream>>>(W_key, WkTh, WkTl, FD_, HD_);
        transconv<<<g, 256, 0, stream>>>(Wf1, Wf1T, nullptr, FD_, HD_);
    }
    {
        dim3 g((WD_ + 31) / 32, (HD_ + 31) / 32);
        transconv<<<g, 256, 0, stream>>>(W_query, WqTh, WqTl, WD_, HD_);
    }
    {
        dim3 g((600 + 31) / 32, (256 + 31) / 32);
        transconv<<<g, 256, 0, stream>>>(Wr1, Wr1T, nullptr, 600, 256);
    }
    conv_bf16<<<(N_ * WD_ + 255) / 256, 256, 0, stream>>>(embed, embH, N_ * WD_);

    // --- prop matrix ---
    zero_kernel<<<(N_ * N_ + 255) / 256, 256, 0, stream>>>(prop, N_ * N_);
    edge_mfma<<<(E_ + 63) / 64, 256, 0, stream>>>(embH, edges, Wr1T, br1, Wr2, br2, prop);

    // --- attention path (MFMA) ---
    // keys = feats @ W_key + b_key -> hi/lo bf16 planes [3136][512]  (split precision)
    {
        dim3 g(HD_ / 64, (B_ * L_ + 63) / 64, 1);
        mm_mfma<OUT_SPLIT, true, false><<<g, 128, 0, stream>>>(
            feats, WkTh, WkTl, b_key, keysH, keysL, B_ * L_, HD_, FD_, 0, 0, 0);
    }
    // F1^T = (feats @ Wf1)^T -> bf16 [b][512][196]
    {
        dim3 g(HD_ / 64, (B_ * L_ + 63) / 64, 1);
        mm_mfma<OUT_TRANS, false, false><<<g, 128, 0, stream>>>(
            feats, Wf1T, nullptr, nullptr, F1T, nullptr, B_ * L_, HD_, FD_, 0, 0, 0);
    }
    // queries = embed @ W_query + b_query -> fp32 [1000][512]  (split precision)
    {
        dim3 g(HD_ / 64, (N_ + 63) / 64, 1);
        mm_mfma<OUT_F32, true, false><<<g, 128, 0, stream>>>(
            embed, WqTh, WqTl, b_query, queries, nullptr, N_, HD_, WD_, 0, 0, 0);
    }
    // scores[b] = queries @ keys[b]^T -> fp32 out_attn [b][1000][196]  (split)
    {
        dim3 g((L_ + 63) / 64, (N_ + 63) / 64, B_);
        mm_mfma<OUT_F32, true, false><<<g, 128, 0, stream>>>(
            queries, keysH, keysL, nullptr, out_attn, nullptr, N_, L_, HD_,
            0, (long)L_ * HD_, (long)N_ * L_);
    }
    softmax_rows<L_><<<(B_ * N_ * 64 + 255) / 256, 256, 0, stream>>>(out_attn, B_ * N_);

    // h1 = relu(attn @ F1 + bf1) -> bf16 [b][1000][512]
    {
        dim3 g(HD_ / 64, (N_ + 63) / 64, B_);
        mm_mfma<OUT_BF16, false, true><<<g, 128, 0, stream>>>(
            out_attn, F1T, nullptr, bf1, h1b, nullptr, N_, HD_, L_,
            (long)N_ * L_, (long)HD_ * L_, (long)N_ * HD_);
    }
    // hidden (transposed [N][B][D]) = h1 @ Wf2 + bf2
    h0_kernel<<<(B_ * N_ * 64 + 255) / 256, 256, 0, stream>>>(h1b, Wf2, bf2, Ht0, B_ * N_);

    // --- recurrence: 5 fused steps, ping-pong ---
    {
        float* hin = Ht0;
        float* hout = Ht1;
        for (int step = 0; step < TMAX_; step++) {
            step_kernel<<<(N_ + 31) / 32, 256, 0, stream>>>(prop, hin, hout,
                                                            W_ih, b_ih, W_hh, b_hh);
            float* tmp = hin; hin = hout; hout = tmp;
        }
        out_kernel<<<(B_ * N_ * 64 + 255) / 256, 256, 0, stream>>>(hin, Wo1, bo1, Wo2, bo2,
                                                                   out_logits, B_ * N_);
    }
}

// Round 4
// 1238.337 us; speedup vs baseline: 1.8272x; 1.2093x over previous
//
#include <hip/hip_runtime.h>
#include <hip/hip_bf16.h>
#include <math.h>

// Problem constants
#define B_   16
#define L_   196
#define FD_  2048
#define N_   1000
#define WD_  300
#define HD_  512
#define DD_  5
#define E_   50000
#define TMAX_ 5
#define NIMG_ 1000

typedef __attribute__((ext_vector_type(8))) short bf16x8;
typedef __attribute__((ext_vector_type(4))) float f32x4;

__device__ __forceinline__ short bf_hi(float x) {
    unsigned u = __float_as_uint(x);
    unsigned r = u + 0x7fffu + ((u >> 16) & 1u);
    return (short)(r >> 16);
}
__device__ __forceinline__ float bf2f_(short s) {
    return __uint_as_float(((unsigned)(unsigned short)s) << 16);
}

// ---------------------------------------------------------------------------
// Transpose + convert: in fp32 [K][N] -> outH (and optionally outL) bf16 [N][K]
// ---------------------------------------------------------------------------
__global__ __launch_bounds__(256) void transconv(
    const float* __restrict__ in, short* __restrict__ outH, short* __restrict__ outL,
    int K, int N)
{
    __shared__ float tile[32][33];
    int k0 = blockIdx.x * 32, n0 = blockIdx.y * 32;
    int t = threadIdx.x;
    int tr = t >> 5, tc = t & 31;
    #pragma unroll
    for (int i = 0; i < 4; i++) {
        int k = k0 + tr + i * 8, n = n0 + tc;
        tile[tr + i * 8][tc] = (k < K && n < N) ? in[(long)k * N + n] : 0.f;
    }
    __syncthreads();
    #pragma unroll
    for (int i = 0; i < 4; i++) {
        int n = n0 + tr + i * 8, k = k0 + tc;
        if (n < N && k < K) {
            float x = tile[tc][tr + i * 8];
            short hi = bf_hi(x);
            outH[(long)n * K + k] = hi;
            if (outL) outL[(long)n * K + k] = bf_hi(x - bf2f_(hi));
        }
    }
}

// elementwise fp32 -> bf16 (hi plane only)
__global__ void conv_bf16(const float* __restrict__ in, short* __restrict__ out, int n)
{
    int i = blockIdx.x * blockDim.x + threadIdx.x;
    if (i < n) out[i] = bf_hi(in[i]);
}

// ---------------------------------------------------------------------------
// MFMA GEMM: C = act(A @ B^T + bias), A fp32 [M][K] (inline bf16 hi/lo),
// B bf16 planes [N][K]. 64x64 tile, 128 threads (2 waves, each 32x64), BK=32.
// SPLIT: hi/lo segments FUSED into the k-loop: one staging pass per k-step,
// 3 MFMA terms (AhBh + AlBh + AhBl) into the same accumulators.
// OUTMODE: 0=fp32, 1=bf16 hi/lo planes, 2=transposed bf16 [b][N][196], 3=bf16.
// ---------------------------------------------------------------------------
#define OUT_F32   0
#define OUT_SPLIT 1
#define OUT_TRANS 2
#define OUT_BF16  3

template<int OUTMODE, bool SPLIT, bool RELU>
__global__ __launch_bounds__(128) void mm_mfma(
    const float* __restrict__ A, const short* __restrict__ Bh,
    const short* __restrict__ Bl, const float* __restrict__ bias,
    void* __restrict__ C0, void* __restrict__ C1,
    int M, int N, int K, long sA, long sB, long sC)
{
    __shared__ short AsH[64][40];
    __shared__ short AsL[SPLIT ? 64 : 1][40];
    __shared__ short BsH[64][40];
    __shared__ short BsL[SPLIT ? 64 : 1][40];
    int z = blockIdx.z;
    A += (long)z * sA;
    Bh += (long)z * sB;
    if (SPLIT) Bl += (long)z * sB;
    int t = threadIdx.x;
    int lane = t & 63, w = t >> 6;
    int q = lane >> 4, r = lane & 15;
    int row0 = blockIdx.y * 64, col0 = blockIdx.x * 64;
    f32x4 zero4 = {0.f, 0.f, 0.f, 0.f};
    f32x4 acc[2][4];
    #pragma unroll
    for (int i = 0; i < 2; i++)
        #pragma unroll
        for (int j = 0; j < 4; j++) acc[i][j] = zero4;

    int Ksteps = (K + 31) >> 5;
    for (int ks = 0; ks < Ksteps; ks++) {
        int k0 = ks * 32;
        // --- stage A (64 x 32): fp32 -> bf16 hi (+lo)
        {
            int arow = t >> 1, kc = (t & 1) * 16;
            int gm = row0 + arow;
            const float* ap = A + (long)gm * K + k0 + kc;
            short th[16], tl[16];
            if (gm < M && k0 + 32 <= K) {
                #pragma unroll
                for (int u4 = 0; u4 < 4; u4++) {
                    float4 v = *(const float4*)(ap + u4 * 4);
                    float xs[4] = {v.x, v.y, v.z, v.w};
                    #pragma unroll
                    for (int j = 0; j < 4; j++) {
                        short hi = bf_hi(xs[j]);
                        th[u4 * 4 + j] = hi;
                        if (SPLIT) tl[u4 * 4 + j] = bf_hi(xs[j] - bf2f_(hi));
                    }
                }
            } else {
                #pragma unroll
                for (int j = 0; j < 16; j++) {
                    int gk = k0 + kc + j;
                    float x = (gm < M && gk < K) ? ap[j] : 0.f;
                    short hi = bf_hi(x);
                    th[j] = hi;
                    if (SPLIT) tl[j] = bf_hi(x - bf2f_(hi));
                }
            }
            *(int4*)&AsH[arow][kc] = *(int4*)&th[0];
            *(int4*)&AsH[arow][kc + 8] = *(int4*)&th[8];
            if (SPLIT) {
                *(int4*)&AsL[arow][kc] = *(int4*)&tl[0];
                *(int4*)&AsL[arow][kc + 8] = *(int4*)&tl[8];
            }
        }
        // --- stage B hi (+lo) from bf16 [N][K]
        {
            int brow = t >> 1, kc = (t & 1) * 16;
            int gn = col0 + brow;
            const short* bph = Bh + (long)gn * K + k0 + kc;
            short th[16], tl[16];
            if (gn < N && k0 + 32 <= K) {
                #pragma unroll
                for (int u2 = 0; u2 < 4; u2++)
                    *(int2*)&th[u2 * 4] = *(const int2*)(bph + u2 * 4);
                if (SPLIT) {
                    const short* bpl = Bl + (long)gn * K + k0 + kc;
                    #pragma unroll
                    for (int u2 = 0; u2 < 4; u2++)
                        *(int2*)&tl[u2 * 4] = *(const int2*)(bpl + u2 * 4);
                }
            } else {
                #pragma unroll
                for (int j = 0; j < 16; j++) {
                    int gk = k0 + kc + j;
                    bool ok = (gn < N && gk < K);
                    th[j] = ok ? bph[j] : (short)0;
                    if (SPLIT) tl[j] = ok ? Bl[(long)gn * K + gk] : (short)0;
                }
            }
            *(int4*)&BsH[brow][kc] = *(int4*)&th[0];
            *(int4*)&BsH[brow][kc + 8] = *(int4*)&th[8];
            if (SPLIT) {
                *(int4*)&BsL[brow][kc] = *(int4*)&tl[0];
                *(int4*)&BsL[brow][kc + 8] = *(int4*)&tl[8];
            }
        }
        __syncthreads();
        bf16x8 ah0 = *(const bf16x8*)&AsH[w * 32 + r][q * 8];
        bf16x8 ah1 = *(const bf16x8*)&AsH[w * 32 + 16 + r][q * 8];
        bf16x8 al0, al1;
        if (SPLIT) {
            al0 = *(const bf16x8*)&AsL[w * 32 + r][q * 8];
            al1 = *(const bf16x8*)&AsL[w * 32 + 16 + r][q * 8];
        }
        #pragma unroll
        for (int ct = 0; ct < 4; ct++) {
            bf16x8 bh = *(const bf16x8*)&BsH[ct * 16 + r][q * 8];
            acc[0][ct] = __builtin_amdgcn_mfma_f32_16x16x32_bf16(ah0, bh, acc[0][ct], 0, 0, 0);
            acc[1][ct] = __builtin_amdgcn_mfma_f32_16x16x32_bf16(ah1, bh, acc[1][ct], 0, 0, 0);
            if (SPLIT) {
                acc[0][ct] = __builtin_amdgcn_mfma_f32_16x16x32_bf16(al0, bh, acc[0][ct], 0, 0, 0);
                acc[1][ct] = __builtin_amdgcn_mfma_f32_16x16x32_bf16(al1, bh, acc[1][ct], 0, 0, 0);
                bf16x8 bl = *(const bf16x8*)&BsL[ct * 16 + r][q * 8];
                acc[0][ct] = __builtin_amdgcn_mfma_f32_16x16x32_bf16(ah0, bl, acc[0][ct], 0, 0, 0);
                acc[1][ct] = __builtin_amdgcn_mfma_f32_16x16x32_bf16(ah1, bl, acc[1][ct], 0, 0, 0);
            }
        }
        __syncthreads();
    }
    // --- epilogue
    #pragma unroll
    for (int i = 0; i < 2; i++) {
        #pragma unroll
        for (int ct = 0; ct < 4; ct++) {
            #pragma unroll
            for (int reg = 0; reg < 4; reg++) {
                int m = row0 + w * 32 + i * 16 + q * 4 + reg;
                int n = col0 + ct * 16 + r;
                if (m >= M || n >= N) continue;
                float v = acc[i][ct][reg];
                if (bias) v += bias[n];
                if (RELU) v = fmaxf(v, 0.f);
                long idx = (long)z * sC + (long)m * N + n;
                if (OUTMODE == OUT_F32) {
                    ((float*)C0)[idx] = v;
                } else if (OUTMODE == OUT_SPLIT) {
                    short hi = bf_hi(v);
                    ((short*)C0)[idx] = hi;
                    ((short*)C1)[idx] = bf_hi(v - bf2f_(hi));
                } else if (OUTMODE == OUT_BF16) {
                    ((short*)C0)[idx] = bf_hi(v);
                } else { // OUT_TRANS: [b][N][196] from m = b*196 + l
                    int b = m / 196, l = m - b * 196;
                    ((short*)C0)[((long)b * N + n) * 196 + l] = bf_hi(v);
                }
            }
        }
    }
}

// ---------------------------------------------------------------------------
// Edge MLP via MFMA: 64 edges x 256 units/block, K=600 (pad 608).
// ---------------------------------------------------------------------------
__global__ __launch_bounds__(256) void edge_mfma(
    const short* __restrict__ embedH, const int* __restrict__ edges,
    const short* __restrict__ Wr1T, const float* __restrict__ br1,
    const float* __restrict__ Wr2, const float* __restrict__ br2,
    float* __restrict__ prop)
{
    __shared__ short As[64][40];
    __shared__ short Bs[256][40];
    __shared__ int src[64], dst[64];
    __shared__ float part[64][5];
    int t = threadIdx.x;
    int e0 = blockIdx.x * 64;
    if (t < 64) {
        int e = e0 + t;
        src[t] = (e < E_) ? edges[e] : 0;
        dst[t] = (e < E_) ? edges[E_ + e] : 0;
    }
    __syncthreads();
    int lane = t & 63, w = t >> 6, q = lane >> 4, r = lane & 15;
    f32x4 zero4 = {0.f, 0.f, 0.f, 0.f};
    f32x4 acc[4][4];
    #pragma unroll
    for (int i = 0; i < 4; i++)
        #pragma unroll
        for (int j = 0; j < 4; j++) acc[i][j] = zero4;

    for (int ks = 0; ks < 19; ks++) {
        int k0 = ks * 32;
        {
            int arow = t >> 2, kc = (t & 3) * 8;
            int gk0 = k0 + kc;
            int sn = src[arow], dn = dst[arow];
            short tmp[8];
            if (gk0 + 8 <= 300) {
                const short* p = embedH + (long)sn * 300 + gk0;
                *(int2*)&tmp[0] = *(const int2*)p;
                *(int2*)&tmp[4] = *(const int2*)(p + 4);
            } else if (gk0 >= 300 && gk0 + 8 <= 600) {
                const short* p = embedH + (long)dn * 300 + (gk0 - 300);
                *(int2*)&tmp[0] = *(const int2*)p;
                *(int2*)&tmp[4] = *(const int2*)(p + 4);
            } else {
                #pragma unroll
                for (int j = 0; j < 8; j++) {
                    int gk = gk0 + j;
                    short v = 0;
                    if (gk < 300) v = embedH[(long)sn * 300 + gk];
                    else if (gk < 600) v = embedH[(long)dn * 300 + gk - 300];
                    tmp[j] = v;
                }
            }
            *(int4*)&As[arow][kc] = *(int4*)&tmp[0];
        }
        #pragma unroll
        for (int i = 0; i < 4; i++) {
            int n = i * 64 + (t >> 2), kc = (t & 3) * 8;
            int gk0 = k0 + kc;
            short tmp[8];
            if (gk0 + 8 <= 600) {
                const short* p = Wr1T + (long)n * 600 + gk0;
                *(int2*)&tmp[0] = *(const int2*)p;
                *(int2*)&tmp[4] = *(const int2*)(p + 4);
            } else {
                #pragma unroll
                for (int j = 0; j < 8; j++) tmp[j] = 0;
            }
            *(int4*)&Bs[n][kc] = *(int4*)&tmp[0];
        }
        __syncthreads();
        bf16x8 af[4], bfr[4];
        #pragma unroll
        for (int rt = 0; rt < 4; rt++) af[rt] = *(const bf16x8*)&As[rt * 16 + r][q * 8];
        #pragma unroll
        for (int ct = 0; ct < 4; ct++) bfr[ct] = *(const bf16x8*)&Bs[w * 64 + ct * 16 + r][q * 8];
        #pragma unroll
        for (int rt = 0; rt < 4; rt++)
            #pragma unroll
            for (int ct = 0; ct < 4; ct++)
                acc[rt][ct] = __builtin_amdgcn_mfma_f32_16x16x32_bf16(af[rt], bfr[ct], acc[rt][ct], 0, 0, 0);
        __syncthreads();
    }
    float b1v[4], w2v[4];
    #pragma unroll
    for (int ct = 0; ct < 4; ct++) {
        int u = w * 64 + ct * 16 + r;
        b1v[ct] = br1[u];
        w2v[ct] = Wr2[u];
    }
    #pragma unroll
    for (int rt = 0; rt < 4; rt++) {
        #pragma unroll
        for (int reg = 0; reg < 4; reg++) {
            float s = 0.f;
            #pragma unroll
            for (int ct = 0; ct < 4; ct++)
                s = fmaf(fmaxf(acc[rt][ct][reg] + b1v[ct], 0.f), w2v[ct], s);
            s += __shfl_xor(s, 1);
            s += __shfl_xor(s, 2);
            s += __shfl_xor(s, 4);
            s += __shfl_xor(s, 8);
            if (r == 0) part[rt * 16 + q * 4 + reg][w] = s;
        }
    }
    __syncthreads();
    if (t < 64 && e0 + t < E_) {
        float s = part[t][0] + part[t][1] + part[t][2] + part[t][3];
        atomicAdd(&prop[(long)src[t] * N_ + dst[t]], tanhf(s + br2[0]));
    }
}

// ---------------------------------------------------------------------------
__global__ void pooled_kernel(const float* __restrict__ feats, float* __restrict__ pooled)
{
    int idx = blockIdx.x * blockDim.x + threadIdx.x;
    if (idx >= B_ * FD_) return;
    int b = idx / FD_, f = idx % FD_;
    const float* p = feats + (long)b * L_ * FD_ + f;
    float acc = 0.f;
    for (int l = 0; l < L_; l++) acc += p[(long)l * FD_];
    pooled[idx] = acc * (1.0f / L_);
}

__global__ void clf_partial(const float* __restrict__ pooled, const float* __restrict__ W,
                            const float* __restrict__ bias, float* __restrict__ out)
{
    int i = blockIdx.x * blockDim.x + threadIdx.x;
    int ks = blockIdx.y;
    if (i >= B_ * NIMG_) return;
    int b = i / NIMG_, n = i % NIMG_;
    const float* p = pooled + (long)b * FD_ + ks * 256;
    const float* w = W + (long)(ks * 256) * NIMG_ + n;
    float acc = (ks == 0) ? bias[n] : 0.f;
    #pragma unroll 4
    for (int k = 0; k < 256; k++) acc = fmaf(p[k], w[(long)k * NIMG_], acc);
    atomicAdd(&out[i], acc);
}

template<int NCOLS>
__global__ void softmax_rows(float* __restrict__ X, int rows)
{
    int gid = blockIdx.x * blockDim.x + threadIdx.x;
    int wave = gid >> 6, lane = gid & 63;
    if (wave >= rows) return;
    float* row = X + (long)wave * NCOLS;
    const int PER = (NCOLS + 63) / 64;
    float v[PER];
    float m = -1e30f;
    int cnt = 0;
    for (int k = lane; k < NCOLS; k += 64) { v[cnt] = row[k]; m = fmaxf(m, v[cnt]); cnt++; }
    #pragma unroll
    for (int off = 32; off; off >>= 1) m = fmaxf(m, __shfl_xor(m, off));
    float s = 0.f;
    for (int i = 0; i < cnt; i++) { v[i] = expf(v[i] - m); s += v[i]; }
    #pragma unroll
    for (int off = 32; off; off >>= 1) s += __shfl_xor(s, off);
    float inv = 1.f / s;
    cnt = 0;
    for (int k = lane; k < NCOLS; k += 64) row[k] = v[cnt++] * inv;
}

// h0: reads h1 (bf16 [r][512]), writes transposed [N][B][D]
__global__ void h0_kernel(const short* __restrict__ h1, const float* __restrict__ Wf2,
                          const float* __restrict__ bf2, float* __restrict__ h0t, int rows)
{
    int gid = blockIdx.x * blockDim.x + threadIdx.x;
    int wave = gid >> 6, lane = gid & 63;
    if (wave >= rows) return;
    const short* row = h1 + (long)wave * HD_;
    float acc[DD_] = {};
    for (int k = lane; k < HD_; k += 64) {
        float v = bf2f_(row[k]);
        #pragma unroll
        for (int d = 0; d < DD_; d++) acc[d] = fmaf(v, Wf2[k * DD_ + d], acc[d]);
    }
    #pragma unroll
    for (int d = 0; d < DD_; d++)
        #pragma unroll
        for (int off = 32; off; off >>= 1) acc[d] += __shfl_down(acc[d], off);
    if (lane == 0) {
        int b = wave / N_, n = wave % N_;
        #pragma unroll
        for (int d = 0; d < DD_; d++)
            h0t[(long)n * (B_ * DD_) + b * DD_ + d] = acc[d] + bf2[d];
    }
}

__global__ void zero_kernel(float* __restrict__ p, int n)
{
    int i = blockIdx.x * blockDim.x + threadIdx.x;
    if (i < n) p[i] = 0.f;
}

// Fused recurrence step on transposed hidden H[N][B*D=80]
__global__ __launch_bounds__(256) void step_kernel(
    const float* __restrict__ prop, const float* __restrict__ Hin,
    float* __restrict__ Hout,
    const float* __restrict__ W_ih, const float* __restrict__ b_ih,
    const float* __restrict__ W_hh, const float* __restrict__ b_hh)
{
    __shared__ float As[16][34];
    __shared__ float Bs[16][80];
    int t = threadIdx.x;
    int x = t & 15, y = t >> 4;
    int n0 = blockIdx.x * 32;
    float acc[2][5] = {};
    for (int k0 = 0; k0 < N_; k0 += 16) {
        {
            int id = t * 2;
            int nn = id >> 4, kb = id & 15;
            int gn = n0 + nn, gk = k0 + kb;
            float2 v = make_float2(0.f, 0.f);
            if (gn < N_) {
                if (gk + 1 < N_)      v = *(const float2*)(prop + (long)gn * N_ + gk);
                else if (gk < N_)     v.x = prop[(long)gn * N_ + gk];
            }
            As[kb][nn] = v.x;
            As[kb + 1][nn] = v.y;
        }
        #pragma unroll
        for (int i = 0; i < 5; i++) {
            int id = i * 256 + t;
            int g = k0 * 80 + id;
            Bs[id / 80][id % 80] = (g < N_ * 80) ? Hin[g] : 0.f;
        }
        __syncthreads();
        #pragma unroll
        for (int kk = 0; kk < 16; kk++) {
            float a0 = As[kk][y * 2], a1 = As[kk][y * 2 + 1];
            #pragma unroll
            for (int j = 0; j < 5; j++) {
                float b = Bs[kk][x * 5 + j];
                acc[0][j] = fmaf(a0, b, acc[0][j]);
                acc[1][j] = fmaf(a1, b, acc[1][j]);
            }
        }
        __syncthreads();
    }
    #pragma unroll
    for (int i = 0; i < 2; i++) {
        int n = n0 + y * 2 + i;
        if (n >= N_) continue;
        float xv[DD_], h[DD_];
        #pragma unroll
        for (int j = 0; j < DD_; j++) {
            xv[j] = tanhf(acc[i][j]);
            h[j] = Hin[(long)n * 80 + x * DD_ + j];
        }
        float gi[3 * DD_], gh[3 * DD_];
        #pragma unroll
        for (int g = 0; g < 3 * DD_; g++) {
            float a = b_ih[g], c = b_hh[g];
            #pragma unroll
            for (int k = 0; k < DD_; k++) {
                a = fmaf(xv[k], W_ih[g * DD_ + k], a);
                c = fmaf(h[k], W_hh[g * DD_ + k], c);
            }
            gi[g] = a; gh[g] = c;
        }
        #pragma unroll
        for (int j = 0; j < DD_; j++) {
            float rr = 1.f / (1.f + expf(-(gi[j] + gh[j])));
            float zz = 1.f / (1.f + expf(-(gi[DD_ + j] + gh[DD_ + j])));
            float nn2 = tanhf(gi[2 * DD_ + j] + rr * gh[2 * DD_ + j]);
            Hout[(long)n * 80 + x * DD_ + j] = (1.f - zz) * nn2 + zz * h[j];
        }
    }
}

__global__ void out_kernel(const float* __restrict__ ht, const float* __restrict__ Wo1,
                           const float* __restrict__ bo1, const float* __restrict__ Wo2,
                           const float* __restrict__ bo2, float* __restrict__ logits, int rows)
{
    int gid = blockIdx.x * blockDim.x + threadIdx.x;
    int wave = gid >> 6, lane = gid & 63;
    if (wave >= rows) return;
    int b = wave / N_, n = wave % N_;
    float x[DD_];
    #pragma unroll
    for (int i = 0; i < DD_; i++) x[i] = ht[(long)n * (B_ * DD_) + b * DD_ + i];
    float acc = 0.f;
    for (int j = lane; j < HD_; j += 64) {
        float h = bo1[j];
        #pragma unroll
        for (int d = 0; d < DD_; d++) h = fmaf(x[d], Wo1[d * HD_ + j], h);
        h = fmaxf(h, 0.f);
        acc = fmaf(h, Wo2[j], acc);
    }
    #pragma unroll
    for (int off = 32; off; off >>= 1) acc += __shfl_down(acc, off);
    if (lane == 0) logits[wave] = acc + bo2[0];
}

// ---------------------------------------------------------------------------
extern "C" void kernel_launch(void* const* d_in, const int* in_sizes, int n_in,
                              void* d_out, int out_size, void* d_ws, size_t ws_size,
                              hipStream_t stream)
{
    const float* feats   = (const float*)d_in[0];
    const float* embed   = (const float*)d_in[1];
    const int*   edges   = (const int*)  d_in[2];
    const float* W_key   = (const float*)d_in[3];
    const float* b_key   = (const float*)d_in[4];
    const float* W_query = (const float*)d_in[5];
    const float* b_query = (const float*)d_in[6];
    const float* Wf1     = (const float*)d_in[7];
    const float* bf1     = (const float*)d_in[8];
    const float* Wf2     = (const float*)d_in[9];
    const float* bf2     = (const float*)d_in[10];
    const float* Wr1     = (const float*)d_in[11];
    const float* br1     = (const float*)d_in[12];
    const float* Wr2     = (const float*)d_in[13];
    const float* br2     = (const float*)d_in[14];
    const float* Wo1     = (const float*)d_in[15];
    const float* bo1     = (const float*)d_in[16];
    const float* Wo2     = (const float*)d_in[17];
    const float* bo2     = (const float*)d_in[18];
    const float* W_ih    = (const float*)d_in[19];
    const float* b_ih    = (const float*)d_in[20];
    const float* W_hh    = (const float*)d_in[21];
    const float* b_hh    = (const float*)d_in[22];
    const float* W_clf   = (const float*)d_in[23];
    const float* b_clf   = (const float*)d_in[24];

    float* out_logits = (float*)d_out;
    float* out_attn   = out_logits + B_ * N_;
    float* out_img    = out_attn + (long)B_ * N_ * L_;

    char* p = (char*)d_ws;
    auto alloc = [&](size_t bytes) { void* r = (void*)p; p += (bytes + 255) & ~(size_t)255; return r; };
    float* pooled  = (float*)alloc((size_t)B_ * FD_ * 4);
    short* WkTh    = (short*)alloc((size_t)HD_ * FD_ * 2);
    short* WkTl    = (short*)alloc((size_t)HD_ * FD_ * 2);
    short* WqTh    = (short*)alloc((size_t)HD_ * WD_ * 2);
    short* WqTl    = (short*)alloc((size_t)HD_ * WD_ * 2);
    short* Wf1T    = (short*)alloc((size_t)HD_ * FD_ * 2);
    short* Wr1T    = (short*)alloc((size_t)256 * 600 * 2);
    short* embH    = (short*)alloc((size_t)N_ * WD_ * 2);
    short* keysH   = (short*)alloc((size_t)B_ * L_ * HD_ * 2);
    short* keysL   = (short*)alloc((size_t)B_ * L_ * HD_ * 2);
    float* queries = (float*)alloc((size_t)N_ * HD_ * 4);
    short* F1T     = (short*)alloc((size_t)B_ * HD_ * L_ * 2);
    short* h1b     = (short*)alloc((size_t)B_ * N_ * HD_ * 2);
    float* prop    = (float*)alloc((size_t)N_ * N_ * 4);
    float* Ht0     = (float*)alloc((size_t)N_ * B_ * DD_ * 4);
    float* Ht1     = (float*)alloc((size_t)N_ * B_ * DD_ * 4);

    // --- imagenet classifier path ---
    pooled_kernel<<<(B_ * FD_ + 255) / 256, 256, 0, stream>>>(feats, pooled);
    zero_kernel<<<(B_ * NIMG_ + 255) / 256, 256, 0, stream>>>(out_img, B_ * NIMG_);
    {
        dim3 g((B_ * NIMG_ + 255) / 256, FD_ / 256);
        clf_partial<<<g, 256, 0, stream>>>(pooled, W_clf, b_clf, out_img);
    }
    softmax_rows<NIMG_><<<(B_ * 64 + 255) / 256, 256, 0, stream>>>(out_img, B_);

    // --- weight pre-transpose/convert ---
    {
        dim3 g((FD_ + 31) / 32, (HD_ + 31) / 32);
        transconv<<<g, 256, 0, stream>>>(W_key, WkTh, WkTl, FD_, HD_);
        transconv<<<g, 256, 0, stream>>>(Wf1, Wf1T, nullptr, FD_, HD_);
    }
    {
        dim3 g((WD_ + 31) / 32, (HD_ + 31) / 32);
        transconv<<<g, 256, 0, stream>>>(W_query, WqTh, WqTl, WD_, HD_);
    }
    {
        dim3 g((600 + 31) / 32, (256 + 31) / 32);
        transconv<<<g, 256, 0, stream>>>(Wr1, Wr1T, nullptr, 600, 256);
    }
    conv_bf16<<<(N_ * WD_ + 255) / 256, 256, 0, stream>>>(embed, embH, N_ * WD_);

    // --- prop matrix ---
    zero_kernel<<<(N_ * N_ + 255) / 256, 256, 0, stream>>>(prop, N_ * N_);
    edge_mfma<<<(E_ + 63) / 64, 256, 0, stream>>>(embH, edges, Wr1T, br1, Wr2, br2, prop);

    // --- attention path (MFMA, fused hi/lo segments) ---
    // keys = feats @ W_key + b_key -> hi/lo bf16 planes [3136][512]
    {
        dim3 g(HD_ / 64, (B_ * L_ + 63) / 64, 1);
        mm_mfma<OUT_SPLIT, true, false><<<g, 128, 0, stream>>>(
            feats, WkTh, WkTl, b_key, keysH, keysL, B_ * L_, HD_, FD_, 0, 0, 0);
    }
    // F1^T = (feats @ Wf1)^T -> bf16 [b][512][196]
    {
        dim3 g(HD_ / 64, (B_ * L_ + 63) / 64, 1);
        mm_mfma<OUT_TRANS, false, false><<<g, 128, 0, stream>>>(
            feats, Wf1T, nullptr, nullptr, F1T, nullptr, B_ * L_, HD_, FD_, 0, 0, 0);
    }
    // queries = embed @ W_query + b_query -> fp32 [1000][512]
    {
        dim3 g(HD_ / 64, (N_ + 63) / 64, 1);
        mm_mfma<OUT_F32, true, false><<<g, 128, 0, stream>>>(
            embed, WqTh, WqTl, b_query, queries, nullptr, N_, HD_, WD_, 0, 0, 0);
    }
    // scores[b] = queries @ keys[b]^T -> fp32 out_attn [b][1000][196]
    {
        dim3 g((L_ + 63) / 64, (N_ + 63) / 64, B_);
        mm_mfma<OUT_F32, true, false><<<g, 128, 0, stream>>>(
            queries, keysH, keysL, nullptr, out_attn, nullptr, N_, L_, HD_,
            0, (long)L_ * HD_, (long)N_ * L_);
    }
    softmax_rows<L_><<<(B_ * N_ * 64 + 255) / 256, 256, 0, stream>>>(out_attn, B_ * N_);

    // h1 = relu(attn @ F1 + bf1) -> bf16 [b][1000][512]
    {
        dim3 g(HD_ / 64, (N_ + 63) / 64, B_);
        mm_mfma<OUT_BF16, false, true><<<g, 128, 0, stream>>>(
            out_attn, F1T, nullptr, bf1, h1b, nullptr, N_, HD_, L_,
            (long)N_ * L_, (long)HD_ * L_, (long)N_ * HD_);
    }
    // hidden (transposed [N][B][D]) = h1 @ Wf2 + bf2
    h0_kernel<<<(B_ * N_ * 64 + 255) / 256, 256, 0, stream>>>(h1b, Wf2, bf2, Ht0, B_ * N_);

    // --- recurrence: 5 fused steps, ping-pong ---
    {
        float* hin = Ht0;
        float* hout = Ht1;
        for (int step = 0; step < TMAX_; step++) {
            step_kernel<<<(N_ + 31) / 32, 256, 0, stream>>>(prop, hin, hout,
                                                            W_ih, b_ih, W_hh, b_hh);
            float* tmp = hin; hin = hout; hout = tmp;
        }
        out_kernel<<<(B_ * N_ * 64 + 255) / 256, 256, 0, stream>>>(hin, Wo1, bo1, Wo2, bo2,
                                                                   out_logits, B_ * N_);
    }
}

// Round 5
// 752.498 us; speedup vs baseline: 3.0069x; 1.6456x over previous
//
#include <hip/hip_runtime.h>
#include <hip/hip_bf16.h>
#include <math.h>

// Problem constants
#define B_   16
#define L_   196
#define FD_  2048
#define N_   1000
#define WD_  300
#define HD_  512
#define DD_  5
#define E_   50000
#define TMAX_ 5
#define NIMG_ 1000

typedef __attribute__((ext_vector_type(8))) short bf16x8;
typedef __attribute__((ext_vector_type(4))) float f32x4;

__device__ __forceinline__ short bf_hi(float x) {
    unsigned u = __float_as_uint(x);
    unsigned r = u + 0x7fffu + ((u >> 16) & 1u);
    return (short)(r >> 16);
}
__device__ __forceinline__ float bf2f_(short s) {
    return __uint_as_float(((unsigned)(unsigned short)s) << 16);
}

// ---------------------------------------------------------------------------
// Transpose + convert: in fp32 [K][N] -> outH (and optionally outL) bf16 [N][K]
// ---------------------------------------------------------------------------
__global__ __launch_bounds__(256) void transconv(
    const float* __restrict__ in, short* __restrict__ outH, short* __restrict__ outL,
    int K, int N)
{
    __shared__ float tile[32][33];
    int k0 = blockIdx.x * 32, n0 = blockIdx.y * 32;
    int t = threadIdx.x;
    int tr = t >> 5, tc = t & 31;
    #pragma unroll
    for (int i = 0; i < 4; i++) {
        int k = k0 + tr + i * 8, n = n0 + tc;
        tile[tr + i * 8][tc] = (k < K && n < N) ? in[(long)k * N + n] : 0.f;
    }
    __syncthreads();
    #pragma unroll
    for (int i = 0; i < 4; i++) {
        int n = n0 + tr + i * 8, k = k0 + tc;
        if (n < N && k < K) {
            float x = tile[tc][tr + i * 8];
            short hi = bf_hi(x);
            outH[(long)n * K + k] = hi;
            if (outL) outL[(long)n * K + k] = bf_hi(x - bf2f_(hi));
        }
    }
}

// elementwise fp32 -> bf16 (hi plane only)
__global__ void conv_bf16(const float* __restrict__ in, short* __restrict__ out, int n)
{
    int i = blockIdx.x * blockDim.x + threadIdx.x;
    if (i < n) out[i] = bf_hi(in[i]);
}

// ---------------------------------------------------------------------------
// MFMA GEMM: C = act(A @ B^T + bias), A fp32 [M][K] (inline bf16 hi/lo),
// B bf16 planes [N][K]. 64x64 tile, 128 threads (2 waves), BK=32.
// SPLIT: hi/lo fused in k-loop (AhBh + AlBh + AhBl).
// ---------------------------------------------------------------------------
#define OUT_F32   0
#define OUT_SPLIT 1
#define OUT_TRANS 2
#define OUT_BF16  3

template<int OUTMODE, bool SPLIT, bool RELU>
__global__ __launch_bounds__(128) void mm_mfma(
    const float* __restrict__ A, const short* __restrict__ Bh,
    const short* __restrict__ Bl, const float* __restrict__ bias,
    void* __restrict__ C0, void* __restrict__ C1,
    int M, int N, int K, long sA, long sB, long sC)
{
    __shared__ short AsH[64][40];
    __shared__ short AsL[SPLIT ? 64 : 1][40];
    __shared__ short BsH[64][40];
    __shared__ short BsL[SPLIT ? 64 : 1][40];
    int z = blockIdx.z;
    A += (long)z * sA;
    Bh += (long)z * sB;
    if (SPLIT) Bl += (long)z * sB;
    int t = threadIdx.x;
    int lane = t & 63, w = t >> 6;
    int q = lane >> 4, r = lane & 15;
    int row0 = blockIdx.y * 64, col0 = blockIdx.x * 64;
    f32x4 zero4 = {0.f, 0.f, 0.f, 0.f};
    f32x4 acc[2][4];
    #pragma unroll
    for (int i = 0; i < 2; i++)
        #pragma unroll
        for (int j = 0; j < 4; j++) acc[i][j] = zero4;

    int Ksteps = (K + 31) >> 5;
    for (int ks = 0; ks < Ksteps; ks++) {
        int k0 = ks * 32;
        {
            int arow = t >> 1, kc = (t & 1) * 16;
            int gm = row0 + arow;
            const float* ap = A + (long)gm * K + k0 + kc;
            short th[16], tl[16];
            if (gm < M && k0 + 32 <= K) {
                #pragma unroll
                for (int u4 = 0; u4 < 4; u4++) {
                    float4 v = *(const float4*)(ap + u4 * 4);
                    float xs[4] = {v.x, v.y, v.z, v.w};
                    #pragma unroll
                    for (int j = 0; j < 4; j++) {
                        short hi = bf_hi(xs[j]);
                        th[u4 * 4 + j] = hi;
                        if (SPLIT) tl[u4 * 4 + j] = bf_hi(xs[j] - bf2f_(hi));
                    }
                }
            } else {
                #pragma unroll
                for (int j = 0; j < 16; j++) {
                    int gk = k0 + kc + j;
                    float x = (gm < M && gk < K) ? ap[j] : 0.f;
                    short hi = bf_hi(x);
                    th[j] = hi;
                    if (SPLIT) tl[j] = bf_hi(x - bf2f_(hi));
                }
            }
            *(int4*)&AsH[arow][kc] = *(int4*)&th[0];
            *(int4*)&AsH[arow][kc + 8] = *(int4*)&th[8];
            if (SPLIT) {
                *(int4*)&AsL[arow][kc] = *(int4*)&tl[0];
                *(int4*)&AsL[arow][kc + 8] = *(int4*)&tl[8];
            }
        }
        {
            int brow = t >> 1, kc = (t & 1) * 16;
            int gn = col0 + brow;
            const short* bph = Bh + (long)gn * K + k0 + kc;
            short th[16], tl[16];
            if (gn < N && k0 + 32 <= K) {
                #pragma unroll
                for (int u2 = 0; u2 < 4; u2++)
                    *(int2*)&th[u2 * 4] = *(const int2*)(bph + u2 * 4);
                if (SPLIT) {
                    const short* bpl = Bl + (long)gn * K + k0 + kc;
                    #pragma unroll
                    for (int u2 = 0; u2 < 4; u2++)
                        *(int2*)&tl[u2 * 4] = *(const int2*)(bpl + u2 * 4);
                }
            } else {
                #pragma unroll
                for (int j = 0; j < 16; j++) {
                    int gk = k0 + kc + j;
                    bool ok = (gn < N && gk < K);
                    th[j] = ok ? bph[j] : (short)0;
                    if (SPLIT) tl[j] = ok ? Bl[(long)gn * K + gk] : (short)0;
                }
            }
            *(int4*)&BsH[brow][kc] = *(int4*)&th[0];
            *(int4*)&BsH[brow][kc + 8] = *(int4*)&th[8];
            if (SPLIT) {
                *(int4*)&BsL[brow][kc] = *(int4*)&tl[0];
                *(int4*)&BsL[brow][kc + 8] = *(int4*)&tl[8];
            }
        }
        __syncthreads();
        bf16x8 ah0 = *(const bf16x8*)&AsH[w * 32 + r][q * 8];
        bf16x8 ah1 = *(const bf16x8*)&AsH[w * 32 + 16 + r][q * 8];
        bf16x8 al0, al1;
        if (SPLIT) {
            al0 = *(const bf16x8*)&AsL[w * 32 + r][q * 8];
            al1 = *(const bf16x8*)&AsL[w * 32 + 16 + r][q * 8];
        }
        #pragma unroll
        for (int ct = 0; ct < 4; ct++) {
            bf16x8 bh = *(const bf16x8*)&BsH[ct * 16 + r][q * 8];
            acc[0][ct] = __builtin_amdgcn_mfma_f32_16x16x32_bf16(ah0, bh, acc[0][ct], 0, 0, 0);
            acc[1][ct] = __builtin_amdgcn_mfma_f32_16x16x32_bf16(ah1, bh, acc[1][ct], 0, 0, 0);
            if (SPLIT) {
                acc[0][ct] = __builtin_amdgcn_mfma_f32_16x16x32_bf16(al0, bh, acc[0][ct], 0, 0, 0);
                acc[1][ct] = __builtin_amdgcn_mfma_f32_16x16x32_bf16(al1, bh, acc[1][ct], 0, 0, 0);
                bf16x8 bl = *(const bf16x8*)&BsL[ct * 16 + r][q * 8];
                acc[0][ct] = __builtin_amdgcn_mfma_f32_16x16x32_bf16(ah0, bl, acc[0][ct], 0, 0, 0);
                acc[1][ct] = __builtin_amdgcn_mfma_f32_16x16x32_bf16(ah1, bl, acc[1][ct], 0, 0, 0);
            }
        }
        __syncthreads();
    }
    #pragma unroll
    for (int i = 0; i < 2; i++) {
        #pragma unroll
        for (int ct = 0; ct < 4; ct++) {
            #pragma unroll
            for (int reg = 0; reg < 4; reg++) {
                int m = row0 + w * 32 + i * 16 + q * 4 + reg;
                int n = col0 + ct * 16 + r;
                if (m >= M || n >= N) continue;
                float v = acc[i][ct][reg];
                if (bias) v += bias[n];
                if (RELU) v = fmaxf(v, 0.f);
                long idx = (long)z * sC + (long)m * N + n;
                if (OUTMODE == OUT_F32) {
                    ((float*)C0)[idx] = v;
                } else if (OUTMODE == OUT_SPLIT) {
                    short hi = bf_hi(v);
                    ((short*)C0)[idx] = hi;
                    ((short*)C1)[idx] = bf_hi(v - bf2f_(hi));
                } else if (OUTMODE == OUT_BF16) {
                    ((short*)C0)[idx] = bf_hi(v);
                } else { // OUT_TRANS: [b][N][196] from m = b*196 + l
                    int b = m / 196, l = m - b * 196;
                    ((short*)C0)[((long)b * N + n) * 196 + l] = bf_hi(v);
                }
            }
        }
    }
}

// ---------------------------------------------------------------------------
// Edge MLP via MFMA: 64 edges x 256 units/block, K=600 (pad 608).
// ---------------------------------------------------------------------------
__global__ __launch_bounds__(256) void edge_mfma(
    const short* __restrict__ embedH, const int* __restrict__ edges,
    const short* __restrict__ Wr1T, const float* __restrict__ br1,
    const float* __restrict__ Wr2, const float* __restrict__ br2,
    float* __restrict__ prop)
{
    __shared__ short As[64][40];
    __shared__ short Bs[256][40];
    __shared__ int src[64], dst[64];
    __shared__ float part[64][5];
    int t = threadIdx.x;
    int e0 = blockIdx.x * 64;
    if (t < 64) {
        int e = e0 + t;
        src[t] = (e < E_) ? edges[e] : 0;
        dst[t] = (e < E_) ? edges[E_ + e] : 0;
    }
    __syncthreads();
    int lane = t & 63, w = t >> 6, q = lane >> 4, r = lane & 15;
    f32x4 zero4 = {0.f, 0.f, 0.f, 0.f};
    f32x4 acc[4][4];
    #pragma unroll
    for (int i = 0; i < 4; i++)
        #pragma unroll
        for (int j = 0; j < 4; j++) acc[i][j] = zero4;

    for (int ks = 0; ks < 19; ks++) {
        int k0 = ks * 32;
        {
            int arow = t >> 2, kc = (t & 3) * 8;
            int gk0 = k0 + kc;
            int sn = src[arow], dn = dst[arow];
            short tmp[8];
            if (gk0 + 8 <= 300) {
                const short* p = embedH + (long)sn * 300 + gk0;
                *(int2*)&tmp[0] = *(const int2*)p;
                *(int2*)&tmp[4] = *(const int2*)(p + 4);
            } else if (gk0 >= 300 && gk0 + 8 <= 600) {
                const short* p = embedH + (long)dn * 300 + (gk0 - 300);
                *(int2*)&tmp[0] = *(const int2*)p;
                *(int2*)&tmp[4] = *(const int2*)(p + 4);
            } else {
                #pragma unroll
                for (int j = 0; j < 8; j++) {
                    int gk = gk0 + j;
                    short v = 0;
                    if (gk < 300) v = embedH[(long)sn * 300 + gk];
                    else if (gk < 600) v = embedH[(long)dn * 300 + gk - 300];
                    tmp[j] = v;
                }
            }
            *(int4*)&As[arow][kc] = *(int4*)&tmp[0];
        }
        #pragma unroll
        for (int i = 0; i < 4; i++) {
            int n = i * 64 + (t >> 2), kc = (t & 3) * 8;
            int gk0 = k0 + kc;
            short tmp[8];
            if (gk0 + 8 <= 600) {
                const short* p = Wr1T + (long)n * 600 + gk0;
                *(int2*)&tmp[0] = *(const int2*)p;
                *(int2*)&tmp[4] = *(const int2*)(p + 4);
            } else {
                #pragma unroll
                for (int j = 0; j < 8; j++) tmp[j] = 0;
            }
            *(int4*)&Bs[n][kc] = *(int4*)&tmp[0];
        }
        __syncthreads();
        bf16x8 af[4], bfr[4];
        #pragma unroll
        for (int rt = 0; rt < 4; rt++) af[rt] = *(const bf16x8*)&As[rt * 16 + r][q * 8];
        #pragma unroll
        for (int ct = 0; ct < 4; ct++) bfr[ct] = *(const bf16x8*)&Bs[w * 64 + ct * 16 + r][q * 8];
        #pragma unroll
        for (int rt = 0; rt < 4; rt++)
            #pragma unroll
            for (int ct = 0; ct < 4; ct++)
                acc[rt][ct] = __builtin_amdgcn_mfma_f32_16x16x32_bf16(af[rt], bfr[ct], acc[rt][ct], 0, 0, 0);
        __syncthreads();
    }
    float b1v[4], w2v[4];
    #pragma unroll
    for (int ct = 0; ct < 4; ct++) {
        int u = w * 64 + ct * 16 + r;
        b1v[ct] = br1[u];
        w2v[ct] = Wr2[u];
    }
    #pragma unroll
    for (int rt = 0; rt < 4; rt++) {
        #pragma unroll
        for (int reg = 0; reg < 4; reg++) {
            float s = 0.f;
            #pragma unroll
            for (int ct = 0; ct < 4; ct++)
                s = fmaf(fmaxf(acc[rt][ct][reg] + b1v[ct], 0.f), w2v[ct], s);
            s += __shfl_xor(s, 1);
            s += __shfl_xor(s, 2);
            s += __shfl_xor(s, 4);
            s += __shfl_xor(s, 8);
            if (r == 0) part[rt * 16 + q * 4 + reg][w] = s;
        }
    }
    __syncthreads();
    if (t < 64 && e0 + t < E_) {
        float s = part[t][0] + part[t][1] + part[t][2] + part[t][3];
        atomicAdd(&prop[(long)src[t] * N_ + dst[t]], tanhf(s + br2[0]));
    }
}

// ---------------------------------------------------------------------------
__global__ void pooled_kernel(const float* __restrict__ feats, float* __restrict__ pooled)
{
    int idx = blockIdx.x * blockDim.x + threadIdx.x;
    if (idx >= B_ * FD_) return;
    int b = idx / FD_, f = idx % FD_;
    const float* p = feats + (long)b * L_ * FD_ + f;
    float acc = 0.f;
    for (int l = 0; l < L_; l++) acc += p[(long)l * FD_];
    pooled[idx] = acc * (1.0f / L_);
}

__global__ void clf_partial(const float* __restrict__ pooled, const float* __restrict__ W,
                            const float* __restrict__ bias, float* __restrict__ out)
{
    int i = blockIdx.x * blockDim.x + threadIdx.x;
    int ks = blockIdx.y;
    if (i >= B_ * NIMG_) return;
    int b = i / NIMG_, n = i % NIMG_;
    const float* p = pooled + (long)b * FD_ + ks * 256;
    const float* w = W + (long)(ks * 256) * NIMG_ + n;
    float acc = (ks == 0) ? bias[n] : 0.f;
    #pragma unroll 4
    for (int k = 0; k < 256; k++) acc = fmaf(p[k], w[(long)k * NIMG_], acc);
    atomicAdd(&out[i], acc);
}

template<int NCOLS>
__global__ void softmax_rows(float* __restrict__ X, int rows)
{
    int gid = blockIdx.x * blockDim.x + threadIdx.x;
    int wave = gid >> 6, lane = gid & 63;
    if (wave >= rows) return;
    float* row = X + (long)wave * NCOLS;
    const int PER = (NCOLS + 63) / 64;
    float v[PER];
    float m = -1e30f;
    int cnt = 0;
    for (int k = lane; k < NCOLS; k += 64) { v[cnt] = row[k]; m = fmaxf(m, v[cnt]); cnt++; }
    #pragma unroll
    for (int off = 32; off; off >>= 1) m = fmaxf(m, __shfl_xor(m, off));
    float s = 0.f;
    for (int i = 0; i < cnt; i++) { v[i] = expf(v[i] - m); s += v[i]; }
    #pragma unroll
    for (int off = 32; off; off >>= 1) s += __shfl_xor(s, off);
    float inv = 1.f / s;
    cnt = 0;
    for (int k = lane; k < NCOLS; k += 64) row[k] = v[cnt++] * inv;
}

// h0: reads h1 (bf16 [r][512]), writes transposed [N][B][D]
__global__ void h0_kernel(const short* __restrict__ h1, const float* __restrict__ Wf2,
                          const float* __restrict__ bf2, float* __restrict__ h0t, int rows)
{
    int gid = blockIdx.x * blockDim.x + threadIdx.x;
    int wave = gid >> 6, lane = gid & 63;
    if (wave >= rows) return;
    const short* row = h1 + (long)wave * HD_;
    float acc[DD_] = {};
    for (int k = lane; k < HD_; k += 64) {
        float v = bf2f_(row[k]);
        #pragma unroll
        for (int d = 0; d < DD_; d++) acc[d] = fmaf(v, Wf2[k * DD_ + d], acc[d]);
    }
    #pragma unroll
    for (int d = 0; d < DD_; d++)
        #pragma unroll
        for (int off = 32; off; off >>= 1) acc[d] += __shfl_down(acc[d], off);
    if (lane == 0) {
        int b = wave / N_, n = wave % N_;
        #pragma unroll
        for (int d = 0; d < DD_; d++)
            h0t[(long)n * (B_ * DD_) + b * DD_ + d] = acc[d] + bf2[d];
    }
}

__global__ void zero_kernel(float* __restrict__ p, int n)
{
    int i = blockIdx.x * blockDim.x + threadIdx.x;
    if (i < n) p[i] = 0.f;
}

// ---------------------------------------------------------------------------
// Recurrence step, one thread per output element.
// H layout: [N][B*D=80]. 250 blocks x 320 threads; thread t -> (n = blk*4+t/80,
// c = t%80). msg[n][c] = tanh(sum_m prop[n][m]*Hin[m][c]); prop loads are
// lane-broadcast (c-group shares address, float4), Hin loads coalesced
// (consecutive c). GRU fused via one LDS exchange (64-thread epilogue).
// ---------------------------------------------------------------------------
__global__ __launch_bounds__(320) void step_kernel(
    const float* __restrict__ prop, const float* __restrict__ Hin,
    float* __restrict__ Hout,
    const float* __restrict__ W_ih, const float* __restrict__ b_ih,
    const float* __restrict__ W_hh, const float* __restrict__ b_hh)
{
    __shared__ float msg[4][80];
    int t = threadIdx.x;
    int nl = t / 80, c = t - nl * 80;
    int n = blockIdx.x * 4 + nl;
    const float* pr = prop + (long)n * N_;
    const float* hc = Hin + c;
    float acc = 0.f;
    #pragma unroll 4
    for (int m4 = 0; m4 < N_; m4 += 4) {
        float4 pv = *(const float4*)(pr + m4);
        acc = fmaf(pv.x, hc[(long)(m4 + 0) * 80], acc);
        acc = fmaf(pv.y, hc[(long)(m4 + 1) * 80], acc);
        acc = fmaf(pv.z, hc[(long)(m4 + 2) * 80], acc);
        acc = fmaf(pv.w, hc[(long)(m4 + 3) * 80], acc);
    }
    msg[nl][c] = tanhf(acc);
    __syncthreads();
    if (t < 64) {
        int nl2 = t >> 4, b = t & 15;
        int n2 = blockIdx.x * 4 + nl2;
        float xv[DD_], h[DD_];
        #pragma unroll
        for (int j = 0; j < DD_; j++) {
            xv[j] = msg[nl2][b * DD_ + j];
            h[j] = Hin[(long)n2 * 80 + b * DD_ + j];
        }
        float gi[3 * DD_], gh[3 * DD_];
        #pragma unroll
        for (int g = 0; g < 3 * DD_; g++) {
            float a = b_ih[g], cc = b_hh[g];
            #pragma unroll
            for (int k = 0; k < DD_; k++) {
                a = fmaf(xv[k], W_ih[g * DD_ + k], a);
                cc = fmaf(h[k], W_hh[g * DD_ + k], cc);
            }
            gi[g] = a; gh[g] = cc;
        }
        #pragma unroll
        for (int j = 0; j < DD_; j++) {
            float rr = 1.f / (1.f + expf(-(gi[j] + gh[j])));
            float zz = 1.f / (1.f + expf(-(gi[DD_ + j] + gh[DD_ + j])));
            float nn2 = tanhf(gi[2 * DD_ + j] + rr * gh[2 * DD_ + j]);
            Hout[(long)n2 * 80 + b * DD_ + j] = (1.f - zz) * nn2 + zz * h[j];
        }
    }
}

__global__ void out_kernel(const float* __restrict__ ht, const float* __restrict__ Wo1,
                           const float* __restrict__ bo1, const float* __restrict__ Wo2,
                           const float* __restrict__ bo2, float* __restrict__ logits, int rows)
{
    int gid = blockIdx.x * blockDim.x + threadIdx.x;
    int wave = gid >> 6, lane = gid & 63;
    if (wave >= rows) return;
    int b = wave / N_, n = wave % N_;
    float x[DD_];
    #pragma unroll
    for (int i = 0; i < DD_; i++) x[i] = ht[(long)n * (B_ * DD_) + b * DD_ + i];
    float acc = 0.f;
    for (int j = lane; j < HD_; j += 64) {
        float h = bo1[j];
        #pragma unroll
        for (int d = 0; d < DD_; d++) h = fmaf(x[d], Wo1[d * HD_ + j], h);
        h = fmaxf(h, 0.f);
        acc = fmaf(h, Wo2[j], acc);
    }
    #pragma unroll
    for (int off = 32; off; off >>= 1) acc += __shfl_down(acc, off);
    if (lane == 0) logits[wave] = acc + bo2[0];
}

// ---------------------------------------------------------------------------
extern "C" void kernel_launch(void* const* d_in, const int* in_sizes, int n_in,
                              void* d_out, int out_size, void* d_ws, size_t ws_size,
                              hipStream_t stream)
{
    const float* feats   = (const float*)d_in[0];
    const float* embed   = (const float*)d_in[1];
    const int*   edges   = (const int*)  d_in[2];
    const float* W_key   = (const float*)d_in[3];
    const float* b_key   = (const float*)d_in[4];
    const float* W_query = (const float*)d_in[5];
    const float* b_query = (const float*)d_in[6];
    const float* Wf1     = (const float*)d_in[7];
    const float* bf1     = (const float*)d_in[8];
    const float* Wf2     = (const float*)d_in[9];
    const float* bf2     = (const float*)d_in[10];
    const float* Wr1     = (const float*)d_in[11];
    const float* br1     = (const float*)d_in[12];
    const float* Wr2     = (const float*)d_in[13];
    const float* br2     = (const float*)d_in[14];
    const float* Wo1     = (const float*)d_in[15];
    const float* bo1     = (const float*)d_in[16];
    const float* Wo2     = (const float*)d_in[17];
    const float* bo2     = (const float*)d_in[18];
    const float* W_ih    = (const float*)d_in[19];
    const float* b_ih    = (const float*)d_in[20];
    const float* W_hh    = (const float*)d_in[21];
    const float* b_hh    = (const float*)d_in[22];
    const float* W_clf   = (const float*)d_in[23];
    const float* b_clf   = (const float*)d_in[24];

    float* out_logits = (float*)d_out;
    float* out_attn   = out_logits + B_ * N_;
    float* out_img    = out_attn + (long)B_ * N_ * L_;

    char* p = (char*)d_ws;
    auto alloc = [&](size_t bytes) { void* r = (void*)p; p += (bytes + 255) & ~(size_t)255; return r; };
    float* pooled  = (float*)alloc((size_t)B_ * FD_ * 4);
    short* WkTh    = (short*)alloc((size_t)HD_ * FD_ * 2);
    short* WkTl    = (short*)alloc((size_t)HD_ * FD_ * 2);
    short* WqTh    = (short*)alloc((size_t)HD_ * WD_ * 2);
    short* WqTl    = (short*)alloc((size_t)HD_ * WD_ * 2);
    short* Wf1T    = (short*)alloc((size_t)HD_ * FD_ * 2);
    short* Wr1T    = (short*)alloc((size_t)256 * 600 * 2);
    short* embH    = (short*)alloc((size_t)N_ * WD_ * 2);
    short* keysH   = (short*)alloc((size_t)B_ * L_ * HD_ * 2);
    short* keysL   = (short*)alloc((size_t)B_ * L_ * HD_ * 2);
    float* queries = (float*)alloc((size_t)N_ * HD_ * 4);
    short* F1T     = (short*)alloc((size_t)B_ * HD_ * L_ * 2);
    short* h1b     = (short*)alloc((size_t)B_ * N_ * HD_ * 2);
    float* prop    = (float*)alloc((size_t)N_ * N_ * 4);
    float* Ht0     = (float*)alloc((size_t)N_ * B_ * DD_ * 4);
    float* Ht1     = (float*)alloc((size_t)N_ * B_ * DD_ * 4);

    // --- imagenet classifier path ---
    pooled_kernel<<<(B_ * FD_ + 255) / 256, 256, 0, stream>>>(feats, pooled);
    zero_kernel<<<(B_ * NIMG_ + 255) / 256, 256, 0, stream>>>(out_img, B_ * NIMG_);
    {
        dim3 g((B_ * NIMG_ + 255) / 256, FD_ / 256);
        clf_partial<<<g, 256, 0, stream>>>(pooled, W_clf, b_clf, out_img);
    }
    softmax_rows<NIMG_><<<(B_ * 64 + 255) / 256, 256, 0, stream>>>(out_img, B_);

    // --- weight pre-transpose/convert ---
    {
        dim3 g((FD_ + 31) / 32, (HD_ + 31) / 32);
        transconv<<<g, 256, 0, stream>>>(W_key, WkTh, WkTl, FD_, HD_);
        transconv<<<g, 256, 0, stream>>>(Wf1, Wf1T, nullptr, FD_, HD_);
    }
    {
        dim3 g((WD_ + 31) / 32, (HD_ + 31) / 32);
        transconv<<<g, 256, 0, stream>>>(W_query, WqTh, WqTl, WD_, HD_);
    }
    {
        dim3 g((600 + 31) / 32, (256 + 31) / 32);
        transconv<<<g, 256, 0, stream>>>(Wr1, Wr1T, nullptr, 600, 256);
    }
    conv_bf16<<<(N_ * WD_ + 255) / 256, 256, 0, stream>>>(embed, embH, N_ * WD_);

    // --- prop matrix ---
    zero_kernel<<<(N_ * N_ + 255) / 256, 256, 0, stream>>>(prop, N_ * N_);
    edge_mfma<<<(E_ + 63) / 64, 256, 0, stream>>>(embH, edges, Wr1T, br1, Wr2, br2, prop);

    // --- attention path (MFMA, fused hi/lo segments) ---
    {
        dim3 g(HD_ / 64, (B_ * L_ + 63) / 64, 1);
        mm_mfma<OUT_SPLIT, true, false><<<g, 128, 0, stream>>>(
            feats, WkTh, WkTl, b_key, keysH, keysL, B_ * L_, HD_, FD_, 0, 0, 0);
    }
    {
        dim3 g(HD_ / 64, (B_ * L_ + 63) / 64, 1);
        mm_mfma<OUT_TRANS, false, false><<<g, 128, 0, stream>>>(
            feats, Wf1T, nullptr, nullptr, F1T, nullptr, B_ * L_, HD_, FD_, 0, 0, 0);
    }
    {
        dim3 g(HD_ / 64, (N_ + 63) / 64, 1);
        mm_mfma<OUT_F32, true, false><<<g, 128, 0, stream>>>(
            embed, WqTh, WqTl, b_query, queries, nullptr, N_, HD_, WD_, 0, 0, 0);
    }
    {
        dim3 g((L_ + 63) / 64, (N_ + 63) / 64, B_);
        mm_mfma<OUT_F32, true, false><<<g, 128, 0, stream>>>(
            queries, keysH, keysL, nullptr, out_attn, nullptr, N_, L_, HD_,
            0, (long)L_ * HD_, (long)N_ * L_);
    }
    softmax_rows<L_><<<(B_ * N_ * 64 + 255) / 256, 256, 0, stream>>>(out_attn, B_ * N_);

    // h1 = relu(attn @ F1 + bf1) -> bf16 [b][1000][512]
    {
        dim3 g(HD_ / 64, (N_ + 63) / 64, B_);
        mm_mfma<OUT_BF16, false, true><<<g, 128, 0, stream>>>(
            out_attn, F1T, nullptr, bf1, h1b, nullptr, N_, HD_, L_,
            (long)N_ * L_, (long)HD_ * L_, (long)N_ * HD_);
    }
    // hidden (transposed [N][B][D]) = h1 @ Wf2 + bf2
    h0_kernel<<<(B_ * N_ * 64 + 255) / 256, 256, 0, stream>>>(h1b, Wf2, bf2, Ht0, B_ * N_);

    // --- recurrence: 5 fused steps, ping-pong ---
    {
        float* hin = Ht0;
        float* hout = Ht1;
        for (int step = 0; step < TMAX_; step++) {
            step_kernel<<<N_ / 4, 320, 0, stream>>>(prop, hin, hout,
                                                    W_ih, b_ih, W_hh, b_hh);
            float* tmp = hin; hin = hout; hout = tmp;
        }
        out_kernel<<<(B_ * N_ * 64 + 255) / 256, 256, 0, stream>>>(hin, Wo1, bo1, Wo2, bo2,
                                                                   out_logits, B_ * N_);
    }
}

// Round 6
// 718.199 us; speedup vs baseline: 3.1505x; 1.0478x over previous
//
#include <hip/hip_runtime.h>
#include <hip/hip_bf16.h>
#include <math.h>

// Problem constants
#define B_   16
#define L_   196
#define FD_  2048
#define N_   1000
#define WD_  300
#define HD_  512
#define DD_  5
#define E_   50000
#define TMAX_ 5
#define NIMG_ 1000

typedef __attribute__((ext_vector_type(8))) short bf16x8;
typedef __attribute__((ext_vector_type(4))) float f32x4;

__device__ __forceinline__ short bf_hi(float x) {
    unsigned u = __float_as_uint(x);
    unsigned r = u + 0x7fffu + ((u >> 16) & 1u);
    return (short)(r >> 16);
}
__device__ __forceinline__ float bf2f_(short s) {
    return __uint_as_float(((unsigned)(unsigned short)s) << 16);
}

// ---------------------------------------------------------------------------
// fp32 -> bf16 hi/lo planes, elementwise (4 per thread)
// ---------------------------------------------------------------------------
__global__ void conv_split(const float* __restrict__ in, short* __restrict__ outH,
                           short* __restrict__ outL, int n4)
{
    int i = blockIdx.x * blockDim.x + threadIdx.x;
    if (i >= n4) return;
    float4 v = *(const float4*)(in + i * 4);
    float xs[4] = {v.x, v.y, v.z, v.w};
    short h[4], l[4];
    #pragma unroll
    for (int j = 0; j < 4; j++) {
        h[j] = bf_hi(xs[j]);
        if (outL) l[j] = bf_hi(xs[j] - bf2f_(h[j]));
    }
    *(int2*)(outH + i * 4) = *(int2*)h;
    if (outL) *(int2*)(outL + i * 4) = *(int2*)l;
}

// ---------------------------------------------------------------------------
// Transpose + convert: in fp32 [K][N] -> outH (and optionally outL) bf16 [N][K]
// ---------------------------------------------------------------------------
__global__ __launch_bounds__(256) void transconv(
    const float* __restrict__ in, short* __restrict__ outH, short* __restrict__ outL,
    int K, int N)
{
    __shared__ float tile[32][33];
    int k0 = blockIdx.x * 32, n0 = blockIdx.y * 32;
    int t = threadIdx.x;
    int tr = t >> 5, tc = t & 31;
    #pragma unroll
    for (int i = 0; i < 4; i++) {
        int k = k0 + tr + i * 8, n = n0 + tc;
        tile[tr + i * 8][tc] = (k < K && n < N) ? in[(long)k * N + n] : 0.f;
    }
    __syncthreads();
    #pragma unroll
    for (int i = 0; i < 4; i++) {
        int n = n0 + tr + i * 8, k = k0 + tc;
        if (n < N && k < K) {
            float x = tile[tc][tr + i * 8];
            short hi = bf_hi(x);
            outH[(long)n * K + k] = hi;
            if (outL) outL[(long)n * K + k] = bf_hi(x - bf2f_(hi));
        }
    }
}

// ---------------------------------------------------------------------------
// bounded 8-short load from a row pointer
// ---------------------------------------------------------------------------
__device__ __forceinline__ void load8s(const short* __restrict__ rowp, bool rowok,
                                       int gk, int K, short* tmp)
{
    if (rowok && gk + 8 <= K) {
        *(int2*)&tmp[0] = *(const int2*)(rowp + gk);
        *(int2*)&tmp[4] = *(const int2*)(rowp + gk + 4);
    } else {
        #pragma unroll
        for (int j = 0; j < 8; j++)
            tmp[j] = (rowok && gk + j < K) ? rowp[gk + j] : (short)0;
    }
}

// ---------------------------------------------------------------------------
// MFMA GEMM v2: C = act(A @ B^T + bias). A and B are bf16 planes [rows][K]
// (hi + optional lo). 64x64 tile, 256 threads (4 waves, each 16 rows x 64
// cols), BK=32, 16x16x32 bf16 MFMA. SPLIT: AhBh + AlBh + AhBl fused in-loop.
// ---------------------------------------------------------------------------
#define OUT_F32   0
#define OUT_SPLIT 1
#define OUT_TRANS 2
#define OUT_BF16  3

template<int OUTMODE, bool SPLIT, bool RELU>
__global__ __launch_bounds__(256) void mm2(
    const short* __restrict__ Ah, const short* __restrict__ Al,
    const short* __restrict__ Bh, const short* __restrict__ Bl,
    const float* __restrict__ bias,
    void* __restrict__ C0, void* __restrict__ C1,
    int M, int N, int K, long sA, long sB, long sC)
{
    __shared__ short AsH[64][40];
    __shared__ short BsH[64][40];
    __shared__ short AsL[SPLIT ? 64 : 1][40];
    __shared__ short BsL[SPLIT ? 64 : 1][40];
    int z = blockIdx.z;
    Ah += (long)z * sA;
    Bh += (long)z * sB;
    if (SPLIT) { Al += (long)z * sA; Bl += (long)z * sB; }
    int t = threadIdx.x;
    int lane = t & 63, w = t >> 6;
    int q = lane >> 4, r = lane & 15;
    int row0 = blockIdx.y * 64, col0 = blockIdx.x * 64;
    f32x4 zero4 = {0.f, 0.f, 0.f, 0.f};
    f32x4 acc[4] = {zero4, zero4, zero4, zero4};

    int srow = t >> 2, kc = (t & 3) * 8;
    int Ksteps = (K + 31) >> 5;
    for (int ks = 0; ks < Ksteps; ks++) {
        int gk = ks * 32 + kc;
        short tmp[8];
        {
            int gm = row0 + srow;
            bool ok = gm < M;
            load8s(Ah + (long)gm * K, ok, gk, K, tmp);
            *(int4*)&AsH[srow][kc] = *(int4*)tmp;
            if (SPLIT) {
                load8s(Al + (long)gm * K, ok, gk, K, tmp);
                *(int4*)&AsL[srow][kc] = *(int4*)tmp;
            }
        }
        {
            int gn = col0 + srow;
            bool ok = gn < N;
            load8s(Bh + (long)gn * K, ok, gk, K, tmp);
            *(int4*)&BsH[srow][kc] = *(int4*)tmp;
            if (SPLIT) {
                load8s(Bl + (long)gn * K, ok, gk, K, tmp);
                *(int4*)&BsL[srow][kc] = *(int4*)tmp;
            }
        }
        __syncthreads();
        bf16x8 ah = *(const bf16x8*)&AsH[w * 16 + r][q * 8];
        bf16x8 al;
        if (SPLIT) al = *(const bf16x8*)&AsL[w * 16 + r][q * 8];
        #pragma unroll
        for (int ct = 0; ct < 4; ct++) {
            bf16x8 bh = *(const bf16x8*)&BsH[ct * 16 + r][q * 8];
            acc[ct] = __builtin_amdgcn_mfma_f32_16x16x32_bf16(ah, bh, acc[ct], 0, 0, 0);
            if (SPLIT) {
                acc[ct] = __builtin_amdgcn_mfma_f32_16x16x32_bf16(al, bh, acc[ct], 0, 0, 0);
                bf16x8 bl = *(const bf16x8*)&BsL[ct * 16 + r][q * 8];
                acc[ct] = __builtin_amdgcn_mfma_f32_16x16x32_bf16(ah, bl, acc[ct], 0, 0, 0);
            }
        }
        __syncthreads();
    }
    #pragma unroll
    for (int ct = 0; ct < 4; ct++) {
        #pragma unroll
        for (int reg = 0; reg < 4; reg++) {
            int m = row0 + w * 16 + q * 4 + reg;
            int n = col0 + ct * 16 + r;
            if (m >= M || n >= N) continue;
            float v = acc[ct][reg];
            if (bias) v += bias[n];
            if (RELU) v = fmaxf(v, 0.f);
            long idx = (long)z * sC + (long)m * N + n;
            if (OUTMODE == OUT_F32) {
                ((float*)C0)[idx] = v;
            } else if (OUTMODE == OUT_SPLIT) {
                short hi = bf_hi(v);
                ((short*)C0)[idx] = hi;
                ((short*)C1)[idx] = bf_hi(v - bf2f_(hi));
            } else if (OUTMODE == OUT_BF16) {
                ((short*)C0)[idx] = bf_hi(v);
            } else { // OUT_TRANS: [b][N][196], m = b*196 + l
                int b = m / 196, l = m - b * 196;
                ((short*)C0)[((long)b * N + n) * 196 + l] = bf_hi(v);
            }
        }
    }
}

// ---------------------------------------------------------------------------
// Edge MLP via MFMA: 64 edges x 256 units/block, K=600.
// ---------------------------------------------------------------------------
__global__ __launch_bounds__(256) void edge_mfma(
    const short* __restrict__ embedH, const int* __restrict__ edges,
    const short* __restrict__ Wr1T, const float* __restrict__ br1,
    const float* __restrict__ Wr2, const float* __restrict__ br2,
    float* __restrict__ prop)
{
    __shared__ short As[64][40];
    __shared__ short Bs[256][40];
    __shared__ int src[64], dst[64];
    __shared__ float part[64][5];
    int t = threadIdx.x;
    int e0 = blockIdx.x * 64;
    if (t < 64) {
        int e = e0 + t;
        src[t] = (e < E_) ? edges[e] : 0;
        dst[t] = (e < E_) ? edges[E_ + e] : 0;
    }
    __syncthreads();
    int lane = t & 63, w = t >> 6, q = lane >> 4, r = lane & 15;
    f32x4 zero4 = {0.f, 0.f, 0.f, 0.f};
    f32x4 acc[4][4];
    #pragma unroll
    for (int i = 0; i < 4; i++)
        #pragma unroll
        for (int j = 0; j < 4; j++) acc[i][j] = zero4;

    for (int ks = 0; ks < 19; ks++) {
        int k0 = ks * 32;
        {
            int arow = t >> 2, kc = (t & 3) * 8;
            int gk0 = k0 + kc;
            int sn = src[arow], dn = dst[arow];
            short tmp[8];
            if (gk0 + 8 <= 300) {
                const short* p = embedH + (long)sn * 300 + gk0;
                *(int2*)&tmp[0] = *(const int2*)p;
                *(int2*)&tmp[4] = *(const int2*)(p + 4);
            } else if (gk0 >= 300 && gk0 + 8 <= 600) {
                const short* p = embedH + (long)dn * 300 + (gk0 - 300);
                *(int2*)&tmp[0] = *(const int2*)p;
                *(int2*)&tmp[4] = *(const int2*)(p + 4);
            } else {
                #pragma unroll
                for (int j = 0; j < 8; j++) {
                    int gk = gk0 + j;
                    short v = 0;
                    if (gk < 300) v = embedH[(long)sn * 300 + gk];
                    else if (gk < 600) v = embedH[(long)dn * 300 + gk - 300];
                    tmp[j] = v;
                }
            }
            *(int4*)&As[arow][kc] = *(int4*)&tmp[0];
        }
        #pragma unroll
        for (int i = 0; i < 4; i++) {
            int n = i * 64 + (t >> 2), kc = (t & 3) * 8;
            int gk0 = k0 + kc;
            short tmp[8];
            if (gk0 + 8 <= 600) {
                const short* p = Wr1T + (long)n * 600 + gk0;
                *(int2*)&tmp[0] = *(const int2*)p;
                *(int2*)&tmp[4] = *(const int2*)(p + 4);
            } else {
                #pragma unroll
                for (int j = 0; j < 8; j++) tmp[j] = 0;
            }
            *(int4*)&Bs[n][kc] = *(int4*)&tmp[0];
        }
        __syncthreads();
        bf16x8 af[4], bfr[4];
        #pragma unroll
        for (int rt = 0; rt < 4; rt++) af[rt] = *(const bf16x8*)&As[rt * 16 + r][q * 8];
        #pragma unroll
        for (int ct = 0; ct < 4; ct++) bfr[ct] = *(const bf16x8*)&Bs[w * 64 + ct * 16 + r][q * 8];
        #pragma unroll
        for (int rt = 0; rt < 4; rt++)
            #pragma unroll
            for (int ct = 0; ct < 4; ct++)
                acc[rt][ct] = __builtin_amdgcn_mfma_f32_16x16x32_bf16(af[rt], bfr[ct], acc[rt][ct], 0, 0, 0);
        __syncthreads();
    }
    float b1v[4], w2v[4];
    #pragma unroll
    for (int ct = 0; ct < 4; ct++) {
        int u = w * 64 + ct * 16 + r;
        b1v[ct] = br1[u];
        w2v[ct] = Wr2[u];
    }
    #pragma unroll
    for (int rt = 0; rt < 4; rt++) {
        #pragma unroll
        for (int reg = 0; reg < 4; reg++) {
            float s = 0.f;
            #pragma unroll
            for (int ct = 0; ct < 4; ct++)
                s = fmaf(fmaxf(acc[rt][ct][reg] + b1v[ct], 0.f), w2v[ct], s);
            s += __shfl_xor(s, 1);
            s += __shfl_xor(s, 2);
            s += __shfl_xor(s, 4);
            s += __shfl_xor(s, 8);
            if (r == 0) part[rt * 16 + q * 4 + reg][w] = s;
        }
    }
    __syncthreads();
    if (t < 64 && e0 + t < E_) {
        float s = part[t][0] + part[t][1] + part[t][2] + part[t][3];
        atomicAdd(&prop[(long)src[t] * N_ + dst[t]], tanhf(s + br2[0]));
    }
}

// ---------------------------------------------------------------------------
__global__ void pooled_kernel(const float* __restrict__ feats, float* __restrict__ pooled)
{
    int idx = blockIdx.x * blockDim.x + threadIdx.x;
    if (idx >= B_ * FD_) return;
    int b = idx / FD_, f = idx % FD_;
    const float* p = feats + (long)b * L_ * FD_ + f;
    float acc = 0.f;
    for (int l = 0; l < L_; l++) acc += p[(long)l * FD_];
    pooled[idx] = acc * (1.0f / L_);
}

__global__ void clf_partial(const float* __restrict__ pooled, const float* __restrict__ W,
                            const float* __restrict__ bias, float* __restrict__ out)
{
    int i = blockIdx.x * blockDim.x + threadIdx.x;
    int ks = blockIdx.y;
    if (i >= B_ * NIMG_) return;
    int b = i / NIMG_, n = i % NIMG_;
    const float* p = pooled + (long)b * FD_ + ks * 256;
    const float* w = W + (long)(ks * 256) * NIMG_ + n;
    float acc = (ks == 0) ? bias[n] : 0.f;
    #pragma unroll 4
    for (int k = 0; k < 256; k++) acc = fmaf(p[k], w[(long)k * NIMG_], acc);
    atomicAdd(&out[i], acc);
}

// in-place row softmax; optional bf16 copy of the result
template<int NCOLS>
__global__ void softmax_rows(float* __restrict__ X, short* __restrict__ Xb, int rows)
{
    int gid = blockIdx.x * blockDim.x + threadIdx.x;
    int wave = gid >> 6, lane = gid & 63;
    if (wave >= rows) return;
    float* row = X + (long)wave * NCOLS;
    const int PER = (NCOLS + 63) / 64;
    float v[PER];
    float m = -1e30f;
    int cnt = 0;
    for (int k = lane; k < NCOLS; k += 64) { v[cnt] = row[k]; m = fmaxf(m, v[cnt]); cnt++; }
    #pragma unroll
    for (int off = 32; off; off >>= 1) m = fmaxf(m, __shfl_xor(m, off));
    float s = 0.f;
    for (int i = 0; i < cnt; i++) { v[i] = expf(v[i] - m); s += v[i]; }
    #pragma unroll
    for (int off = 32; off; off >>= 1) s += __shfl_xor(s, off);
    float inv = 1.f / s;
    cnt = 0;
    for (int k = lane; k < NCOLS; k += 64) {
        float val = v[cnt++] * inv;
        row[k] = val;
        if (Xb) Xb[(long)wave * NCOLS + k] = bf_hi(val);
    }
}

// h0: reads h1 (bf16 [r][512]), writes transposed [N][B][D]
__global__ void h0_kernel(const short* __restrict__ h1, const float* __restrict__ Wf2,
                          const float* __restrict__ bf2, float* __restrict__ h0t, int rows)
{
    int gid = blockIdx.x * blockDim.x + threadIdx.x;
    int wave = gid >> 6, lane = gid & 63;
    if (wave >= rows) return;
    const short* row = h1 + (long)wave * HD_;
    float acc[DD_] = {};
    for (int k = lane; k < HD_; k += 64) {
        float v = bf2f_(row[k]);
        #pragma unroll
        for (int d = 0; d < DD_; d++) acc[d] = fmaf(v, Wf2[k * DD_ + d], acc[d]);
    }
    #pragma unroll
    for (int d = 0; d < DD_; d++)
        #pragma unroll
        for (int off = 32; off; off >>= 1) acc[d] += __shfl_down(acc[d], off);
    if (lane == 0) {
        int b = wave / N_, n = wave % N_;
        #pragma unroll
        for (int d = 0; d < DD_; d++)
            h0t[(long)n * (B_ * DD_) + b * DD_ + d] = acc[d] + bf2[d];
    }
}

__global__ void zero_kernel(float* __restrict__ p, int n)
{
    int i = blockIdx.x * blockDim.x + threadIdx.x;
    if (i < n) p[i] = 0.f;
}

// ---------------------------------------------------------------------------
// Recurrence step, one thread per output element (H [N][B*D=80]).
// ---------------------------------------------------------------------------
__global__ __launch_bounds__(320) void step_kernel(
    const float* __restrict__ prop, const float* __restrict__ Hin,
    float* __restrict__ Hout,
    const float* __restrict__ W_ih, const float* __restrict__ b_ih,
    const float* __restrict__ W_hh, const float* __restrict__ b_hh)
{
    __shared__ float msg[4][80];
    int t = threadIdx.x;
    int nl = t / 80, c = t - nl * 80;
    int n = blockIdx.x * 4 + nl;
    const float* pr = prop + (long)n * N_;
    const float* hc = Hin + c;
    float acc = 0.f;
    #pragma unroll 4
    for (int m4 = 0; m4 < N_; m4 += 4) {
        float4 pv = *(const float4*)(pr + m4);
        acc = fmaf(pv.x, hc[(long)(m4 + 0) * 80], acc);
        acc = fmaf(pv.y, hc[(long)(m4 + 1) * 80], acc);
        acc = fmaf(pv.z, hc[(long)(m4 + 2) * 80], acc);
        acc = fmaf(pv.w, hc[(long)(m4 + 3) * 80], acc);
    }
    msg[nl][c] = tanhf(acc);
    __syncthreads();
    if (t < 64) {
        int nl2 = t >> 4, b = t & 15;
        int n2 = blockIdx.x * 4 + nl2;
        float xv[DD_], h[DD_];
        #pragma unroll
        for (int j = 0; j < DD_; j++) {
            xv[j] = msg[nl2][b * DD_ + j];
            h[j] = Hin[(long)n2 * 80 + b * DD_ + j];
        }
        float gi[3 * DD_], gh[3 * DD_];
        #pragma unroll
        for (int g = 0; g < 3 * DD_; g++) {
            float a = b_ih[g], cc = b_hh[g];
            #pragma unroll
            for (int k = 0; k < DD_; k++) {
                a = fmaf(xv[k], W_ih[g * DD_ + k], a);
                cc = fmaf(h[k], W_hh[g * DD_ + k], cc);
            }
            gi[g] = a; gh[g] = cc;
        }
        #pragma unroll
        for (int j = 0; j < DD_; j++) {
            float rr = 1.f / (1.f + expf(-(gi[j] + gh[j])));
            float zz = 1.f / (1.f + expf(-(gi[DD_ + j] + gh[DD_ + j])));
            float nn2 = tanhf(gi[2 * DD_ + j] + rr * gh[2 * DD_ + j]);
            Hout[(long)n2 * 80 + b * DD_ + j] = (1.f - zz) * nn2 + zz * h[j];
        }
    }
}

__global__ void out_kernel(const float* __restrict__ ht, const float* __restrict__ Wo1,
                           const float* __restrict__ bo1, const float* __restrict__ Wo2,
                           const float* __restrict__ bo2, float* __restrict__ logits, int rows)
{
    int gid = blockIdx.x * blockDim.x + threadIdx.x;
    int wave = gid >> 6, lane = gid & 63;
    if (wave >= rows) return;
    int b = wave / N_, n = wave % N_;
    float x[DD_];
    #pragma unroll
    for (int i = 0; i < DD_; i++) x[i] = ht[(long)n * (B_ * DD_) + b * DD_ + i];
    float acc = 0.f;
    for (int j = lane; j < HD_; j += 64) {
        float h = bo1[j];
        #pragma unroll
        for (int d = 0; d < DD_; d++) h = fmaf(x[d], Wo1[d * HD_ + j], h);
        h = fmaxf(h, 0.f);
        acc = fmaf(h, Wo2[j], acc);
    }
    #pragma unroll
    for (int off = 32; off; off >>= 1) acc += __shfl_down(acc, off);
    if (lane == 0) logits[wave] = acc + bo2[0];
}

// ---------------------------------------------------------------------------
extern "C" void kernel_launch(void* const* d_in, const int* in_sizes, int n_in,
                              void* d_out, int out_size, void* d_ws, size_t ws_size,
                              hipStream_t stream)
{
    const float* feats   = (const float*)d_in[0];
    const float* embed   = (const float*)d_in[1];
    const int*   edges   = (const int*)  d_in[2];
    const float* W_key   = (const float*)d_in[3];
    const float* b_key   = (const float*)d_in[4];
    const float* W_query = (const float*)d_in[5];
    const float* b_query = (const float*)d_in[6];
    const float* Wf1     = (const float*)d_in[7];
    const float* bf1     = (const float*)d_in[8];
    const float* Wf2     = (const float*)d_in[9];
    const float* bf2     = (const float*)d_in[10];
    const float* Wr1     = (const float*)d_in[11];
    const float* br1     = (const float*)d_in[12];
    const float* Wr2     = (const float*)d_in[13];
    const float* br2     = (const float*)d_in[14];
    const float* Wo1     = (const float*)d_in[15];
    const float* bo1     = (const float*)d_in[16];
    const float* Wo2     = (const float*)d_in[17];
    const float* bo2     = (const float*)d_in[18];
    const float* W_ih    = (const float*)d_in[19];
    const float* b_ih    = (const float*)d_in[20];
    const float* W_hh    = (const float*)d_in[21];
    const float* b_hh    = (const float*)d_in[22];
    const float* W_clf   = (const float*)d_in[23];
    const float* b_clf   = (const float*)d_in[24];

    float* out_logits = (float*)d_out;
    float* out_attn   = out_logits + B_ * N_;
    float* out_img    = out_attn + (long)B_ * N_ * L_;

    char* p = (char*)d_ws;
    auto alloc = [&](size_t bytes) { void* r = (void*)p; p += (bytes + 255) & ~(size_t)255; return r; };
    float* pooled  = (float*)alloc((size_t)B_ * FD_ * 4);
    short* featsH  = (short*)alloc((size_t)B_ * L_ * FD_ * 2);
    short* featsL  = (short*)alloc((size_t)B_ * L_ * FD_ * 2);
    short* WkTh    = (short*)alloc((size_t)HD_ * FD_ * 2);
    short* WkTl    = (short*)alloc((size_t)HD_ * FD_ * 2);
    short* WqTh    = (short*)alloc((size_t)HD_ * WD_ * 2);
    short* WqTl    = (short*)alloc((size_t)HD_ * WD_ * 2);
    short* Wf1T    = (short*)alloc((size_t)HD_ * FD_ * 2);
    short* Wr1T    = (short*)alloc((size_t)256 * 600 * 2);
    short* embH    = (short*)alloc((size_t)N_ * WD_ * 2);
    short* embL    = (short*)alloc((size_t)N_ * WD_ * 2);
    short* keysH   = (short*)alloc((size_t)B_ * L_ * HD_ * 2);
    short* keysL   = (short*)alloc((size_t)B_ * L_ * HD_ * 2);
    short* qH      = (short*)alloc((size_t)N_ * HD_ * 2);
    short* qL      = (short*)alloc((size_t)N_ * HD_ * 2);
    short* attnH   = (short*)alloc((size_t)B_ * N_ * L_ * 2);
    short* F1T     = (short*)alloc((size_t)B_ * HD_ * L_ * 2);
    short* h1b     = (short*)alloc((size_t)B_ * N_ * HD_ * 2);
    float* prop    = (float*)alloc((size_t)N_ * N_ * 4);
    float* Ht0     = (float*)alloc((size_t)N_ * B_ * DD_ * 4);
    float* Ht1     = (float*)alloc((size_t)N_ * B_ * DD_ * 4);

    // --- imagenet classifier path ---
    pooled_kernel<<<(B_ * FD_ + 255) / 256, 256, 0, stream>>>(feats, pooled);
    zero_kernel<<<(B_ * NIMG_ + 255) / 256, 256, 0, stream>>>(out_img, B_ * NIMG_);
    {
        dim3 g((B_ * NIMG_ + 255) / 256, FD_ / 256);
        clf_partial<<<g, 256, 0, stream>>>(pooled, W_clf, b_clf, out_img);
    }
    softmax_rows<NIMG_><<<(B_ * 64 + 255) / 256, 256, 0, stream>>>(out_img, nullptr, B_);

    // --- operand pre-conversion ---
    {
        int n4 = B_ * L_ * FD_ / 4;
        conv_split<<<(n4 + 255) / 256, 256, 0, stream>>>(feats, featsH, featsL, n4);
    }
    {
        int n4 = N_ * WD_ / 4;
        conv_split<<<(n4 + 255) / 256, 256, 0, stream>>>(embed, embH, embL, n4);
    }
    {
        dim3 g((FD_ + 31) / 32, (HD_ + 31) / 32);
        transconv<<<g, 256, 0, stream>>>(W_key, WkTh, WkTl, FD_, HD_);
        transconv<<<g, 256, 0, stream>>>(Wf1, Wf1T, nullptr, FD_, HD_);
    }
    {
        dim3 g((WD_ + 31) / 32, (HD_ + 31) / 32);
        transconv<<<g, 256, 0, stream>>>(W_query, WqTh, WqTl, WD_, HD_);
    }
    {
        dim3 g((600 + 31) / 32, (256 + 31) / 32);
        transconv<<<g, 256, 0, stream>>>(Wr1, Wr1T, nullptr, 600, 256);
    }

    // --- prop matrix ---
    zero_kernel<<<(N_ * N_ + 255) / 256, 256, 0, stream>>>(prop, N_ * N_);
    edge_mfma<<<(E_ + 63) / 64, 256, 0, stream>>>(embH, edges, Wr1T, br1, Wr2, br2, prop);

    // --- attention path (MFMA on pre-converted planes) ---
    // keys = feats @ W_key + b_key -> hi/lo planes [3136][512]
    {
        dim3 g(HD_ / 64, (B_ * L_ + 63) / 64, 1);
        mm2<OUT_SPLIT, true, false><<<g, 256, 0, stream>>>(
            featsH, featsL, WkTh, WkTl, b_key, keysH, keysL,
            B_ * L_, HD_, FD_, 0, 0, 0);
    }
    // F1^T = (feats @ Wf1)^T -> bf16 [b][512][196]
    {
        dim3 g(HD_ / 64, (B_ * L_ + 63) / 64, 1);
        mm2<OUT_TRANS, false, false><<<g, 256, 0, stream>>>(
            featsH, nullptr, Wf1T, nullptr, nullptr, F1T, nullptr,
            B_ * L_, HD_, FD_, 0, 0, 0);
    }
    // queries = embed @ W_query + b_query -> hi/lo planes [1000][512]
    {
        dim3 g(HD_ / 64, (N_ + 63) / 64, 1);
        mm2<OUT_SPLIT, true, false><<<g, 256, 0, stream>>>(
            embH, embL, WqTh, WqTl, b_query, qH, qL, N_, HD_, WD_, 0, 0, 0);
    }
    // scores[b] = queries @ keys[b]^T -> fp32 out_attn [b][1000][196]
    {
        dim3 g((L_ + 63) / 64, (N_ + 63) / 64, B_);
        mm2<OUT_F32, true, false><<<g, 256, 0, stream>>>(
            qH, qL, keysH, keysL, nullptr, out_attn, nullptr, N_, L_, HD_,
            0, (long)L_ * HD_, (long)N_ * L_);
    }
    // softmax over 196, also emits bf16 copy for h1's A operand
    softmax_rows<L_><<<(B_ * N_ * 64 + 255) / 256, 256, 0, stream>>>(out_attn, attnH, B_ * N_);

    // h1 = relu(attn @ F1 + bf1) -> bf16 [b][1000][512]
    {
        dim3 g(HD_ / 64, (N_ + 63) / 64, B_);
        mm2<OUT_BF16, false, true><<<g, 256, 0, stream>>>(
            attnH, nullptr, F1T, nullptr, bf1, h1b, nullptr, N_, HD_, L_,
            (long)N_ * L_, (long)HD_ * L_, (long)N_ * HD_);
    }
    // hidden (transposed [N][B][D]) = h1 @ Wf2 + bf2
    h0_kernel<<<(B_ * N_ * 64 + 255) / 256, 256, 0, stream>>>(h1b, Wf2, bf2, Ht0, B_ * N_);

    // --- recurrence: 5 fused steps, ping-pong ---
    {
        float* hin = Ht0;
        float* hout = Ht1;
        for (int step = 0; step < TMAX_; step++) {
            step_kernel<<<N_ / 4, 320, 0, stream>>>(prop, hin, hout,
                                                    W_ih, b_ih, W_hh, b_hh);
            float* tmp = hin; hin = hout; hout = tmp;
        }
        out_kernel<<<(B_ * N_ * 64 + 255) / 256, 256, 0, stream>>>(hin, Wo1, bo1, Wo2, bo2,
                                                                   out_logits, B_ * N_);
    }
}